// Round 8
// baseline (516.922 us; speedup 1.0000x reference)
//
#include <hip/hip_runtime.h>
#include <hip/hip_bf16.h>

typedef unsigned short u16;
typedef unsigned int   u32;
using bf16x8 = __attribute__((ext_vector_type(8))) short;
using f32x4  = __attribute__((ext_vector_type(4))) float;

#define AS1 __attribute__((address_space(1)))
#define AS3 __attribute__((address_space(3)))

static constexpr int S_   = 1024;
static constexpr int D_   = 4096;
static constexpr int H_   = 32;
static constexpr int KVH_ = 8;
static constexpr int HD_  = 128;
static constexpr int NQKV = H_*HD_ + 2*KVH_*HD_;   // 6144

__device__ __forceinline__ u16 f2bf(float f) {
  union { float f; u32 u; } v; v.f = f;
  u32 r = v.u + 0x7FFFu + ((v.u >> 16) & 1u);      // RTNE
  return (u16)(r >> 16);
}

// ---------------- x f32 -> bf16 ----------------
__global__ void k_convert(const float* __restrict__ src, u16* __restrict__ dst, int n4) {
  int i = blockIdx.x * blockDim.x + threadIdx.x;
  if (i >= n4) return;
  float4 v = ((const float4*)src)[i];
  ushort4 o;
  o.x = f2bf(v.x); o.y = f2bf(v.y); o.z = f2bf(v.z); o.w = f2bf(v.w);
  ((ushort4*)dst)[i] = o;
}

// ---------------- W [K][N] f32 -> Wt [N][K] bf16 ----------------
__global__ void k_transpose_w(const float* __restrict__ src, u16* __restrict__ dst,
                              int K, int N) {
  __shared__ float t[32][33];
  int k0 = blockIdx.y * 32, n0 = blockIdx.x * 32;
  int tx = threadIdx.x, ty = threadIdx.y;           // (32,8)
#pragma unroll
  for (int i = 0; i < 4; ++i)
    t[ty + i*8][tx] = src[(size_t)(k0 + ty + i*8) * N + n0 + tx];
  __syncthreads();
#pragma unroll
  for (int i = 0; i < 4; ++i)
    dst[(size_t)(n0 + ty + i*8) * K + k0 + tx] = f2bf(t[tx][ty + i*8]);
}

// ---------------- V [BG][S][HD] bf16 -> Vt [BG][HD][S] bf16 ----------------
__global__ void k_transpose_v(const u16* __restrict__ src, u16* __restrict__ dst) {
  __shared__ u16 t[32][33];
  int bg = blockIdx.z;
  int s0 = blockIdx.x * 32, h0 = blockIdx.y * 32;
  src += (size_t)bg * S_ * HD_;
  dst += (size_t)bg * S_ * HD_;
  int tx = threadIdx.x, ty = threadIdx.y;
#pragma unroll
  for (int i = 0; i < 4; ++i)
    t[ty + i*8][tx] = src[(size_t)(s0 + ty + i*8) * HD_ + h0 + tx];
  __syncthreads();
#pragma unroll
  for (int i = 0; i < 4; ++i)
    dst[(size_t)(h0 + ty + i*8) * S_ + s0 + tx] = t[tx][ty + i*8];
}

// ---------------- RoPE tables: cos/sin [S][64] f32 ----------------
__global__ void k_rope(const int* __restrict__ sidx, float* __restrict__ cosd,
                       float* __restrict__ sind) {
  int i = blockIdx.x * blockDim.x + threadIdx.x;    // S*64
  int s = i >> 6, d = i & 63;
  float pos  = (float)sidx[s];
  float invf = expf(-0.21586735246819178f * (float)d);  // 1e6^(-d/64)
  float ph   = pos * invf;
  cosd[i] = cosf(ph);
  sind[i] = sinf(ph);
}

// ---- 256xBN bf16 GEMM, 8-phase counted-vmcnt pipeline (m201-style, plain HIP) ----
template<int BN>
__global__ __launch_bounds__(512, 2) void k_gemm3(
    const u16* __restrict__ A, const u16* __restrict__ Bt,
    float* __restrict__ C, int N, int K)
{
  constexpr int WN = BN/4, NJ = WN/16, NH = NJ/2;   // BN256: 64/4/2, BN128: 32/2/1
  constexpr int ABYT = 256*128, BBYT = BN*128, STEP = ABYT+BBYT;
  __shared__ __align__(16) char lds[2*STEP];

  const int cpx = (int)gridDim.x >> 3;
  const int wkid = ((int)blockIdx.x & 7)*cpx + ((int)blockIdx.x >> 3);
  const int NT = N / BN;
  const int m0 = (wkid / NT) * 256, n0 = (wkid % NT) * BN;
  const int tid = threadIdx.x, w = tid>>6, lane = tid&63;
  const int l15 = lane&15, l4 = lane>>4;
  const int wr = w>>2, wc = w&3;
  const int row0 = tid>>3;                 // staging row in 64-row chunk
  const int ss = (tid&7) ^ (row0&7);       // pre-swizzled source slot
  const int NK = K >> 6;

  f32x4 acc[8][NJ];
#pragma unroll
  for (int i = 0; i < 8; ++i)
#pragma unroll
    for (int j = 0; j < NJ; ++j) acc[i][j] = (f32x4){0.f,0.f,0.f,0.f};

  bf16x8 af[4][2];
  bf16x8 bf[2][NH][2];

#define CHUNK(kt_, part_, r0c_)                                               \
  __builtin_amdgcn_global_load_lds(                                           \
    (AS1 void*)(((part_) ? Bt + (size_t)(n0 + (r0c_) + row0)*K                \
                         : A  + (size_t)(m0 + (r0c_) + row0)*K)               \
                + (size_t)(kt_)*64 + ss*8),                                   \
    (AS3 void*)(lds + ((kt_)&1)*STEP + (part_)*ABYT + (r0c_)*128 + w*1024),   \
    16, 0, 0)

#define LOAD_A(mh_)                                                           \
  _Pragma("unroll") for (int i = 0; i < 4; ++i)                               \
  _Pragma("unroll") for (int kk = 0; kk < 2; ++kk) {                          \
    int row = wr*128 + (mh_)*64 + i*16 + l15;                                 \
    af[i][kk] = *(const bf16x8*)(lA + row*128 + (((kk*4+l4) ^ (row&7)) << 4)); }

#define LOAD_B(nh_)                                                           \
  _Pragma("unroll") for (int jj = 0; jj < NH; ++jj)                           \
  _Pragma("unroll") for (int kk = 0; kk < 2; ++kk) {                          \
    int row = wc*WN + ((nh_)*NH + jj)*16 + l15;                               \
    bf[nh_][jj][kk] = *(const bf16x8*)(lB + row*128 + (((kk*4+l4) ^ (row&7)) << 4)); }

#define MFMA_PH(mh_, nh_)                                                     \
  __builtin_amdgcn_s_setprio(1);                                              \
  _Pragma("unroll") for (int i = 0; i < 4; ++i)                               \
  _Pragma("unroll") for (int jj = 0; jj < NH; ++jj)                           \
  _Pragma("unroll") for (int kk = 0; kk < 2; ++kk)                            \
    acc[(mh_)*4+i][(nh_)*NH+jj] = __builtin_amdgcn_mfma_f32_16x16x32_bf16(    \
        af[i][kk], bf[nh_][jj][kk], acc[(mh_)*4+i][(nh_)*NH+jj], 0, 0, 0);    \
  __builtin_amdgcn_s_setprio(0);

#define BAR   __builtin_amdgcn_s_barrier()
#define SCHB  __builtin_amdgcn_sched_barrier(0)
#define WLGKM asm volatile("s_waitcnt lgkmcnt(0)" ::: "memory")

  CHUNK(0,0,0); CHUNK(0,0,64); CHUNK(0,0,128); CHUNK(0,0,192);
  CHUNK(0,1,0); CHUNK(0,1,64);
  if constexpr (BN == 256) { CHUNK(0,1,128); CHUNK(0,1,192); }
  CHUNK(1,0,0); CHUNK(1,0,128);
  asm volatile("s_waitcnt vmcnt(2)" ::: "memory");
  BAR; SCHB;

  for (int kt = 0; kt < NK; ++kt) {
    const char* lA = lds + (kt&1)*STEP;
    const char* lB = lA + ABYT;
    LOAD_A(0); LOAD_B(0);
    if (kt+1 < NK) { CHUNK(kt+1,0,64); CHUNK(kt+1,0,192); }
    BAR; WLGKM; SCHB;
    MFMA_PH(0,0);
    BAR;
    LOAD_B(1);
    if (kt+1 < NK) {
      CHUNK(kt+1,1,0); CHUNK(kt+1,1,64);
      if constexpr (BN == 256) { CHUNK(kt+1,1,128); CHUNK(kt+1,1,192); }
    }
    BAR; WLGKM; SCHB;
    MFMA_PH(0,1);
    BAR;
    LOAD_A(1);
    if (kt+2 < NK) { CHUNK(kt+2,0,0); CHUNK(kt+2,0,128); }
    BAR; WLGKM; SCHB;
    MFMA_PH(1,0);
    BAR;
    if (kt+2 < NK) asm volatile("s_waitcnt vmcnt(2)" ::: "memory");
    else           asm volatile("s_waitcnt vmcnt(0)" ::: "memory");
    BAR; WLGKM; SCHB;
    MFMA_PH(1,1);
    BAR;
  }
#undef CHUNK
#undef LOAD_A
#undef LOAD_B
#undef MFMA_PH

#pragma unroll
  for (int i = 0; i < 8; ++i)
#pragma unroll
    for (int j = 0; j < NJ; ++j) {
      int r0 = m0 + wr*128 + i*16 + l4*4;
      int c0 = n0 + wc*WN + j*16 + l15;
#pragma unroll
      for (int r = 0; r < 4; ++r)
        C[(size_t)(r0 + r) * N + c0] = acc[i][j][r];
    }
}

// ---------------- bias + RoPE + pack to [B][H][S][HD] bf16 ----------------
__global__ void k_pack(const float* __restrict__ Cq,
                       const float* __restrict__ bq, const float* __restrict__ bk,
                       const float* __restrict__ bv,
                       const float* __restrict__ cosd, const float* __restrict__ sind,
                       u16* __restrict__ qb, u16* __restrict__ kb, u16* __restrict__ vb) {
  int t = blockIdx.x;
  int b = t >> 10, s = t & 1023;
  const float* row = Cq + (size_t)t * NQKV;
  const float* cs = cosd + s*64;
  const float* sn = sind + s*64;
  const float qscale = 0.08838834764831845f;  // 1/sqrt(HD)
  for (int c = threadIdx.x; c < H_*HD_; c += blockDim.x) {
    int h = c >> 7, d = c & 127;
    float v = row[c] + bq[c];
    float o;
    if (d < 64) { float p = row[c + 64] + bq[c + 64]; o = v*cs[d]    - p*sn[d]; }
    else        { float p = row[c - 64] + bq[c - 64]; o = v*cs[d-64] + p*sn[d-64]; }
    qb[(((size_t)b*H_ + h)*S_ + s)*HD_ + d] = f2bf(o * qscale);
  }
  for (int c = threadIdx.x; c < KVH_*HD_; c += blockDim.x) {
    int g = c >> 7, d = c & 127;
    float v = row[H_*HD_ + c] + bk[c];
    float o;
    if (d < 64) { float p = row[H_*HD_ + c + 64] + bk[c + 64]; o = v*cs[d]    - p*sn[d]; }
    else        { float p = row[H_*HD_ + c - 64] + bk[c - 64]; o = v*cs[d-64] + p*sn[d-64]; }
    size_t idx = (((size_t)b*KVH_ + g)*S_ + s)*HD_ + d;
    kb[idx] = f2bf(o);
    vb[idx] = f2bf(row[H_*HD_ + KVH_*HD_ + c] + bv[c]);
  }
}

// ---------------- causal GQA flash attention (1 chunk per wave, max TLP) ----------
__device__ __forceinline__ void attn_chunk(
    int chunk, const u16* __restrict__ Qh, const u16* __restrict__ Kp,
    const u16* __restrict__ Vp, u16* __restrict__ AOh, int lane, char* Pw)
{
  int l15 = lane & 15, l4 = lane >> 4;
  int qrow0 = chunk * 16;
  int kvmax = chunk >> 2;

  bf16x8 qf[4];
#pragma unroll
  for (int kc = 0; kc < 4; ++kc)
    qf[kc] = *(const bf16x8*)(Qh + (size_t)(qrow0 + l15)*HD_ + kc*32 + l4*8);

  f32x4 o[8];
#pragma unroll
  for (int n = 0; n < 8; ++n) o[n] = (f32x4){0.f,0.f,0.f,0.f};
  float mrow[4] = {-3e38f,-3e38f,-3e38f,-3e38f};
  float lrow[4] = {0.f,0.f,0.f,0.f};

  for (int kv = 0; kv <= kvmax; ++kv) {
    int kvb = kv * 64;
    f32x4 sc[4];
    __builtin_amdgcn_s_setprio(1);
#pragma unroll
    for (int ct = 0; ct < 4; ++ct) {
      f32x4 s4 = (f32x4){0.f,0.f,0.f,0.f};
#pragma unroll
      for (int kc = 0; kc < 4; ++kc) {
        bf16x8 kf = *(const bf16x8*)(Kp + (size_t)(kvb + ct*16 + l15)*HD_ + kc*32 + l4*8);
        s4 = __builtin_amdgcn_mfma_f32_16x16x32_bf16(qf[kc], kf, s4, 0, 0, 0);
      }
      sc[ct] = s4;
    }
    __builtin_amdgcn_s_setprio(0);
    if (kv == kvmax) {
#pragma unroll
      for (int ct = 0; ct < 4; ++ct)
#pragma unroll
        for (int r = 0; r < 4; ++r) {
          int col = kvb + ct*16 + l15;
          int rw  = qrow0 + l4*4 + r;
          if (col > rw) sc[ct][r] = -1e9f;
        }
    }
    float f[4];
#pragma unroll
    for (int r = 0; r < 4; ++r) {
      float mx = fmaxf(fmaxf(sc[0][r], sc[1][r]), fmaxf(sc[2][r], sc[3][r]));
      mx = fmaxf(mx, __shfl_xor(mx, 1));
      mx = fmaxf(mx, __shfl_xor(mx, 2));
      mx = fmaxf(mx, __shfl_xor(mx, 4));
      mx = fmaxf(mx, __shfl_xor(mx, 8));
      float nm = fmaxf(mrow[r], mx);
      f[r] = __expf(mrow[r] - nm);
      mrow[r] = nm;
    }
    float rs[4] = {0.f,0.f,0.f,0.f};
#pragma unroll
    for (int ct = 0; ct < 4; ++ct)
#pragma unroll
      for (int r = 0; r < 4; ++r) {
        float p = __expf(sc[ct][r] - mrow[r]);
        rs[r] += p;
        int row = l4*4 + r, col = ct*16 + l15;
        int byte = row*128 + (((col >> 3) ^ (row & 7)) << 4) + (col & 7)*2;
        *(u16*)(Pw + byte) = f2bf(p);
      }
#pragma unroll
    for (int r = 0; r < 4; ++r) {
      float sum = rs[r];
      sum += __shfl_xor(sum, 1);
      sum += __shfl_xor(sum, 2);
      sum += __shfl_xor(sum, 4);
      sum += __shfl_xor(sum, 8);
      lrow[r] = lrow[r]*f[r] + sum;
    }
#pragma unroll
    for (int n = 0; n < 8; ++n)
#pragma unroll
      for (int r = 0; r < 4; ++r) o[n][r] *= f[r];
    __builtin_amdgcn_s_setprio(1);
#pragma unroll
    for (int kk = 0; kk < 2; ++kk) {
      int prow = l15, pslot = kk*4 + l4;
      bf16x8 pf = *(const bf16x8*)(Pw + prow*128 + ((pslot ^ (prow & 7)) << 4));
#pragma unroll
      for (int n = 0; n < 8; ++n) {
        bf16x8 vf = *(const bf16x8*)(Vp + (size_t)(n*16 + l15)*S_ + kvb + kk*32 + l4*8);
        o[n] = __builtin_amdgcn_mfma_f32_16x16x32_bf16(pf, vf, o[n], 0, 0, 0);
      }
    }
    __builtin_amdgcn_s_setprio(0);
  }
#pragma unroll
  for (int n = 0; n < 8; ++n)
#pragma unroll
    for (int r = 0; r < 4; ++r) {
      int srow = qrow0 + l4*4 + r;
      AOh[(size_t)srow * (H_*HD_) + n*16 + l15] = f2bf(o[n][r] / lrow[r]);
    }
}

// grid (32, H, B), block 128 = 2 waves; each wave owns ONE 16-row chunk.
// 4096 waves total -> 16 waves/CU (the 108-VGPR max), double round-7's TLP.
__global__ __launch_bounds__(128) void k_attn(
    const u16* __restrict__ Q, const u16* __restrict__ Kc,
    const u16* __restrict__ Vt, u16* __restrict__ AO)
{
  int w = threadIdx.x >> 6, lane = threadIdx.x & 63;
  int chunk = blockIdx.x * 2 + w;             // 0..63
  int h = blockIdx.y, b = blockIdx.z, g = h >> 2;
  const u16* Qh = Q  + ((size_t)b*H_   + h) * S_ * HD_;
  const u16* Kp = Kc + ((size_t)b*KVH_ + g) * S_ * HD_;
  const u16* Vp = Vt + ((size_t)b*KVH_ + g) * (size_t)HD_ * S_;   // [HD][S]
  u16* AOh = AO + ((size_t)b*S_) * (H_*HD_) + h*HD_;
  __shared__ u16 Pl[2][1024];
  char* Pw = (char*)&Pl[w][0];

  attn_chunk(chunk, Qh, Kp, Vp, AOh, lane, Pw);
}

extern "C" void kernel_launch(void* const* d_in, const int* in_sizes, int n_in,
                              void* d_out, int out_size, void* d_ws, size_t ws_size,
                              hipStream_t stream) {
  (void)in_sizes; (void)n_in; (void)out_size; (void)ws_size;
  const float* x   = (const float*)d_in[0];
  const int*   sid = (const int*)  d_in[1];
  // d_in[2] = cache (dead), d_in[3] = mask (dead: causal re-derived)
  const float* Wq  = (const float*)d_in[4];
  const float* bq  = (const float*)d_in[5];
  const float* Wk  = (const float*)d_in[6];
  const float* bk  = (const float*)d_in[7];
  const float* Wv  = (const float*)d_in[8];
  const float* bv  = (const float*)d_in[9];
  const float* Wo  = (const float*)d_in[10];
  float* out = (float*)d_out;

  char* ws = (char*)d_ws;
  u16*   xb   = (u16*)  (ws);                    // 16 MB (aliased by AO later)
  u16*   WB   = (u16*)  (ws + 16777216);         // 48 MB  [6144][4096]
  u16*   WoT  = (u16*)  (ws + 67108864);         // 32 MB  [4096][4096]
  float* Cq   = (float*)(ws + 100663296);        // 48 MB  [2048][6144]
  u16*   qb   = (u16*)  (ws + 150994944);        // 16 MB  [B][H][S][HD]
  u16*   kb   = (u16*)  (ws + 167772160);        //  4 MB  [B][KVH][S][HD]
  u16*   vb   = (u16*)  (ws + 171966464);        //  4 MB
  u16*   VT   = (u16*)  (ws + 176160768);        //  4 MB  [B][KVH][HD][S]
  float* cosd = (float*)(ws + 180355072);        // 256 KB
  float* sind = (float*)(ws + 180617216);        // 256 KB (total ~181 MB)
  u16*   AO   = xb;                              // attention output reuses xb

  dim3 tb(32, 8);
  k_convert<<<8192, 256, 0, stream>>>(x, xb, (2048*4096)/4);
  k_transpose_w<<<dim3(128,128), tb, 0, stream>>>(Wq, WB, 4096, 4096);
  k_transpose_w<<<dim3( 32,128), tb, 0, stream>>>(Wk, WB + (size_t)4096*4096, 4096, 1024);
  k_transpose_w<<<dim3( 32,128), tb, 0, stream>>>(Wv, WB + (size_t)5120*4096, 4096, 1024);
  k_transpose_w<<<dim3(128,128), tb, 0, stream>>>(Wo, WoT, 4096, 4096);
  k_rope<<<256, 256, 0, stream>>>(sid, cosd, sind);
  k_gemm3<256><<<192, 512, 0, stream>>>(xb, WB, Cq, NQKV, 4096);
  k_pack<<<2048, 256, 0, stream>>>(Cq, bq, bk, bv, cosd, sind, qb, kb, vb);
  k_transpose_v<<<dim3(32,4,16), tb, 0, stream>>>(vb, VT);
  k_attn<<<dim3(32,32,2), 128, 0, stream>>>(qb, kb, VT, AO);
  k_gemm3<128><<<256, 512, 0, stream>>>(AO, WoT, out, 4096, 4096);
}

// Round 9
// 339.386 us; speedup vs baseline: 1.5231x; 1.5231x over previous
//
#include <hip/hip_runtime.h>
#include <hip/hip_bf16.h>

typedef unsigned short u16;
typedef unsigned int   u32;
using bf16x8 = __attribute__((ext_vector_type(8))) short;
using f32x4  = __attribute__((ext_vector_type(4))) float;

#define AS1 __attribute__((address_space(1)))
#define AS3 __attribute__((address_space(3)))

static constexpr int S_   = 1024;
static constexpr int D_   = 4096;
static constexpr int H_   = 32;
static constexpr int KVH_ = 8;
static constexpr int HD_  = 128;
static constexpr int NQKV = H_*HD_ + 2*KVH_*HD_;   // 6144

__device__ __forceinline__ u16 f2bf(float f) {
  union { float f; u32 u; } v; v.f = f;
  u32 r = v.u + 0x7FFFu + ((v.u >> 16) & 1u);      // RTNE
  return (u16)(r >> 16);
}

// ---------------- x f32 -> bf16 ----------------
__global__ void k_convert(const float* __restrict__ src, u16* __restrict__ dst, int n4) {
  int i = blockIdx.x * blockDim.x + threadIdx.x;
  if (i >= n4) return;
  float4 v = ((const float4*)src)[i];
  ushort4 o;
  o.x = f2bf(v.x); o.y = f2bf(v.y); o.z = f2bf(v.z); o.w = f2bf(v.w);
  ((ushort4*)dst)[i] = o;
}

// ---------------- W [K][N] f32 -> Wt [N][K] bf16 ----------------
__global__ void k_transpose_w(const float* __restrict__ src, u16* __restrict__ dst,
                              int K, int N) {
  __shared__ float t[32][33];
  int k0 = blockIdx.y * 32, n0 = blockIdx.x * 32;
  int tx = threadIdx.x, ty = threadIdx.y;           // (32,8)
#pragma unroll
  for (int i = 0; i < 4; ++i)
    t[ty + i*8][tx] = src[(size_t)(k0 + ty + i*8) * N + n0 + tx];
  __syncthreads();
#pragma unroll
  for (int i = 0; i < 4; ++i)
    dst[(size_t)(n0 + ty + i*8) * K + k0 + tx] = f2bf(t[tx][ty + i*8]);
}

// ---------------- V [BG][S][HD] bf16 -> Vt [BG][HD][S] bf16 ----------------
__global__ void k_transpose_v(const u16* __restrict__ src, u16* __restrict__ dst) {
  __shared__ u16 t[32][33];
  int bg = blockIdx.z;
  int s0 = blockIdx.x * 32, h0 = blockIdx.y * 32;
  src += (size_t)bg * S_ * HD_;
  dst += (size_t)bg * S_ * HD_;
  int tx = threadIdx.x, ty = threadIdx.y;
#pragma unroll
  for (int i = 0; i < 4; ++i)
    t[ty + i*8][tx] = src[(size_t)(s0 + ty + i*8) * HD_ + h0 + tx];
  __syncthreads();
#pragma unroll
  for (int i = 0; i < 4; ++i)
    dst[(size_t)(h0 + ty + i*8) * S_ + s0 + tx] = t[tx][ty + i*8];
}

// ---------------- RoPE tables: cos/sin [S][64] f32 ----------------
__global__ void k_rope(const int* __restrict__ sidx, float* __restrict__ cosd,
                       float* __restrict__ sind) {
  int i = blockIdx.x * blockDim.x + threadIdx.x;    // S*64
  int s = i >> 6, d = i & 63;
  float pos  = (float)sidx[s];
  float invf = expf(-0.21586735246819178f * (float)d);  // 1e6^(-d/64)
  float ph   = pos * invf;
  cosd[i] = cosf(ph);
  sind[i] = sinf(ph);
}

// ---- 256xBN bf16 GEMM, 8-phase counted-vmcnt pipeline (m201-style, plain HIP) ----
template<int BN>
__global__ __launch_bounds__(512, 2) void k_gemm3(
    const u16* __restrict__ A, const u16* __restrict__ Bt,
    float* __restrict__ C, int N, int K)
{
  constexpr int WN = BN/4, NJ = WN/16, NH = NJ/2;   // BN256: 64/4/2, BN128: 32/2/1
  constexpr int ABYT = 256*128, BBYT = BN*128, STEP = ABYT+BBYT;
  __shared__ __align__(16) char lds[2*STEP];

  const int cpx = (int)gridDim.x >> 3;
  const int wkid = ((int)blockIdx.x & 7)*cpx + ((int)blockIdx.x >> 3);
  const int NT = N / BN;
  const int m0 = (wkid / NT) * 256, n0 = (wkid % NT) * BN;
  const int tid = threadIdx.x, w = tid>>6, lane = tid&63;
  const int l15 = lane&15, l4 = lane>>4;
  const int wr = w>>2, wc = w&3;
  const int row0 = tid>>3;                 // staging row in 64-row chunk
  const int ss = (tid&7) ^ (row0&7);       // pre-swizzled source slot
  const int NK = K >> 6;

  f32x4 acc[8][NJ];
#pragma unroll
  for (int i = 0; i < 8; ++i)
#pragma unroll
    for (int j = 0; j < NJ; ++j) acc[i][j] = (f32x4){0.f,0.f,0.f,0.f};

  bf16x8 af[4][2];
  bf16x8 bf[2][NH][2];

#define CHUNK(kt_, part_, r0c_)                                               \
  __builtin_amdgcn_global_load_lds(                                           \
    (AS1 void*)(((part_) ? Bt + (size_t)(n0 + (r0c_) + row0)*K                \
                         : A  + (size_t)(m0 + (r0c_) + row0)*K)               \
                + (size_t)(kt_)*64 + ss*8),                                   \
    (AS3 void*)(lds + ((kt_)&1)*STEP + (part_)*ABYT + (r0c_)*128 + w*1024),   \
    16, 0, 0)

#define LOAD_A(mh_)                                                           \
  _Pragma("unroll") for (int i = 0; i < 4; ++i)                               \
  _Pragma("unroll") for (int kk = 0; kk < 2; ++kk) {                          \
    int row = wr*128 + (mh_)*64 + i*16 + l15;                                 \
    af[i][kk] = *(const bf16x8*)(lA + row*128 + (((kk*4+l4) ^ (row&7)) << 4)); }

#define LOAD_B(nh_)                                                           \
  _Pragma("unroll") for (int jj = 0; jj < NH; ++jj)                           \
  _Pragma("unroll") for (int kk = 0; kk < 2; ++kk) {                          \
    int row = wc*WN + ((nh_)*NH + jj)*16 + l15;                               \
    bf[nh_][jj][kk] = *(const bf16x8*)(lB + row*128 + (((kk*4+l4) ^ (row&7)) << 4)); }

#define MFMA_PH(mh_, nh_)                                                     \
  __builtin_amdgcn_s_setprio(1);                                              \
  _Pragma("unroll") for (int i = 0; i < 4; ++i)                               \
  _Pragma("unroll") for (int jj = 0; jj < NH; ++jj)                           \
  _Pragma("unroll") for (int kk = 0; kk < 2; ++kk)                            \
    acc[(mh_)*4+i][(nh_)*NH+jj] = __builtin_amdgcn_mfma_f32_16x16x32_bf16(    \
        af[i][kk], bf[nh_][jj][kk], acc[(mh_)*4+i][(nh_)*NH+jj], 0, 0, 0);    \
  __builtin_amdgcn_s_setprio(0);

#define BAR   __builtin_amdgcn_s_barrier()
#define SCHB  __builtin_amdgcn_sched_barrier(0)
#define WLGKM asm volatile("s_waitcnt lgkmcnt(0)" ::: "memory")

  CHUNK(0,0,0); CHUNK(0,0,64); CHUNK(0,0,128); CHUNK(0,0,192);
  CHUNK(0,1,0); CHUNK(0,1,64);
  if constexpr (BN == 256) { CHUNK(0,1,128); CHUNK(0,1,192); }
  CHUNK(1,0,0); CHUNK(1,0,128);
  asm volatile("s_waitcnt vmcnt(2)" ::: "memory");
  BAR; SCHB;

  for (int kt = 0; kt < NK; ++kt) {
    const char* lA = lds + (kt&1)*STEP;
    const char* lB = lA + ABYT;
    LOAD_A(0); LOAD_B(0);
    if (kt+1 < NK) { CHUNK(kt+1,0,64); CHUNK(kt+1,0,192); }
    BAR; WLGKM; SCHB;
    MFMA_PH(0,0);
    BAR;
    LOAD_B(1);
    if (kt+1 < NK) {
      CHUNK(kt+1,1,0); CHUNK(kt+1,1,64);
      if constexpr (BN == 256) { CHUNK(kt+1,1,128); CHUNK(kt+1,1,192); }
    }
    BAR; WLGKM; SCHB;
    MFMA_PH(0,1);
    BAR;
    LOAD_A(1);
    if (kt+2 < NK) { CHUNK(kt+2,0,0); CHUNK(kt+2,0,128); }
    BAR; WLGKM; SCHB;
    MFMA_PH(1,0);
    BAR;
    if (kt+2 < NK) asm volatile("s_waitcnt vmcnt(2)" ::: "memory");
    else           asm volatile("s_waitcnt vmcnt(0)" ::: "memory");
    BAR; WLGKM; SCHB;
    MFMA_PH(1,1);
    BAR;
  }
#undef CHUNK
#undef LOAD_A
#undef LOAD_B
#undef MFMA_PH

#pragma unroll
  for (int i = 0; i < 8; ++i)
#pragma unroll
    for (int j = 0; j < NJ; ++j) {
      int r0 = m0 + wr*128 + i*16 + l4*4;
      int c0 = n0 + wc*WN + j*16 + l15;
#pragma unroll
      for (int r = 0; r < 4; ++r)
        C[(size_t)(r0 + r) * N + c0] = acc[i][j][r];
    }
}

// ---------------- bias + RoPE + pack to [B][H][S][HD] bf16 ----------------
__global__ void k_pack(const float* __restrict__ Cq,
                       const float* __restrict__ bq, const float* __restrict__ bk,
                       const float* __restrict__ bv,
                       const float* __restrict__ cosd, const float* __restrict__ sind,
                       u16* __restrict__ qb, u16* __restrict__ kb, u16* __restrict__ vb) {
  int t = blockIdx.x;
  int b = t >> 10, s = t & 1023;
  const float* row = Cq + (size_t)t * NQKV;
  const float* cs = cosd + s*64;
  const float* sn = sind + s*64;
  const float qscale = 0.08838834764831845f;  // 1/sqrt(HD)
  for (int c = threadIdx.x; c < H_*HD_; c += blockDim.x) {
    int h = c >> 7, d = c & 127;
    float v = row[c] + bq[c];
    float o;
    if (d < 64) { float p = row[c + 64] + bq[c + 64]; o = v*cs[d]    - p*sn[d]; }
    else        { float p = row[c - 64] + bq[c - 64]; o = v*cs[d-64] + p*sn[d-64]; }
    qb[(((size_t)b*H_ + h)*S_ + s)*HD_ + d] = f2bf(o * qscale);
  }
  for (int c = threadIdx.x; c < KVH_*HD_; c += blockDim.x) {
    int g = c >> 7, d = c & 127;
    float v = row[H_*HD_ + c] + bk[c];
    float o;
    if (d < 64) { float p = row[H_*HD_ + c + 64] + bk[c + 64]; o = v*cs[d]    - p*sn[d]; }
    else        { float p = row[H_*HD_ + c - 64] + bk[c - 64]; o = v*cs[d-64] + p*sn[d-64]; }
    size_t idx = (((size_t)b*KVH_ + g)*S_ + s)*HD_ + d;
    kb[idx] = f2bf(o);
    vb[idx] = f2bf(row[H_*HD_ + KVH_*HD_ + c] + bv[c]);
  }
}

// ---------------- causal GQA flash attention: block-cooperative LDS-staged K/V -------
// Flat grid 512, 256 thr = 4 waves, 2 blocks/CU. Block processes q-tiles {tA=bx,15-bx}
// SEQUENTIALLY (A finishes -> write O -> reuse regs for B): 17 staged kv-tiles total.
// Per iter: cooperative STAGE of K[64x128]+VT[128x64] (32 KB, dbuf, global_load_lds,
// XOR-swizzle via pre-swizzled global src) -> compute -> vmcnt(0) -> barrier.
// XCD decode: xcd=id&7 pins each XCD's L2 to 2 KV groups (1 MB << 4 MB L2).
__global__ __launch_bounds__(256, 4) void k_attn(
    const u16* __restrict__ Q, const u16* __restrict__ Kc,
    const u16* __restrict__ Vt, u16* __restrict__ AO)
{
  __shared__ __align__(16) char Kls[2][16384];   // [64 rows][16 slots], slot^(row&7) low3
  __shared__ __align__(16) char Vls[2][16384];   // [128 rows][8 slots], slot^(row&7)
  __shared__ u16 Pl[4][1024];

  int id = blockIdx.x;
  int slot = id >> 3;
  int bg   = (id & 7)*2 + (slot & 1);            // b*8+g : 2 groups per XCD
  int rem  = slot >> 1;
  int h_in = rem & 3, bx = rem >> 2;             // bx 0..7
  int b = bg >> 3, g = bg & 7, h = g*4 + h_in;
  int tA = bx, tB = 15 - bx;

  int tid = threadIdx.x, w = tid >> 6, lane = tid & 63;
  int l15 = lane & 15, l4 = lane >> 4;
  const u16* Qh = Q  + ((size_t)b*H_   + h) * S_ * HD_;
  const u16* Kp = Kc + ((size_t)b*KVH_ + g) * S_ * HD_;
  const u16* Vp = Vt + ((size_t)b*KVH_ + g) * (size_t)HD_ * S_;   // [HD][S]
  u16* AOh = AO + ((size_t)b*S_) * (H_*HD_) + h*HD_;
  char* Pw = (char*)&Pl[w][0];

  int kOff[4], vOff[4];
#pragma unroll
  for (int c = 0; c < 4; ++c) {
    int ci = c*256 + tid;
    int krow = ci >> 4, ks = ci & 15;
    kOff[c] = krow * HD_ + ((ks & 8) | ((ks & 7) ^ (krow & 7))) * 8;
    int vrow = ci >> 3, vs = ci & 7;
    vOff[c] = vrow * S_ + (vs ^ (vrow & 7)) * 8;
  }

#define ASTAGE(kv_, bb_) {                                                    \
    const u16* ks_ = Kp + (size_t)(kv_) * 64 * HD_;                           \
    const u16* vs_ = Vp + (size_t)(kv_) * 64;                                 \
    _Pragma("unroll") for (int c = 0; c < 4; ++c) {                           \
      __builtin_amdgcn_global_load_lds((AS1 void*)(ks_ + kOff[c]),            \
          (AS3 void*)(&Kls[bb_][0] + c*4096 + w*1024), 16, 0, 0);             \
      __builtin_amdgcn_global_load_lds((AS1 void*)(vs_ + vOff[c]),            \
          (AS3 void*)(&Vls[bb_][0] + c*4096 + w*1024), 16, 0, 0); } }

  bf16x8 qf[4];
#pragma unroll
  for (int kc = 0; kc < 4; ++kc)
    qf[kc] = *(const bf16x8*)(Qh + (size_t)(tA*64 + w*16 + l15)*HD_ + kc*32 + l4*8);

  f32x4 o[8];
#pragma unroll
  for (int n = 0; n < 8; ++n) o[n] = (f32x4){0.f,0.f,0.f,0.f};
  float mrow[4] = {-3e38f,-3e38f,-3e38f,-3e38f};
  float lrow[4] = {0.f,0.f,0.f,0.f};

  ASTAGE(0, 0);
  asm volatile("s_waitcnt vmcnt(0)" ::: "memory");
  __builtin_amdgcn_s_barrier();

  const int NIT = tA + tB + 2;                   // 17
  int buf = 0;
  for (int it = 0; it < NIT; ++it) {
    bool phA = (it <= tA);
    int kv = phA ? it : it - tA - 1;
    int qt = phA ? tA : tB;
    if (it + 1 < NIT) {
      int kvn = (it + 1 <= tA) ? it + 1 : it - tA;
      ASTAGE(kvn, buf ^ 1);
    }
    const char* Ksb = &Kls[buf][0];
    const char* Vsb = &Vls[buf][0];

    f32x4 sc[4];
    __builtin_amdgcn_s_setprio(1);
#pragma unroll
    for (int ct = 0; ct < 4; ++ct) {
      f32x4 s4 = (f32x4){0.f,0.f,0.f,0.f};
#pragma unroll
      for (int kc = 0; kc < 4; ++kc) {
        int row = ct*16 + l15, s = kc*4 + l4;
        bf16x8 kf = *(const bf16x8*)(Ksb + row*256 + ((((s & 7) ^ (row & 7)) | (s & 8)) << 4));
        s4 = __builtin_amdgcn_mfma_f32_16x16x32_bf16(qf[kc], kf, s4, 0, 0, 0);
      }
      sc[ct] = s4;
    }
    __builtin_amdgcn_s_setprio(0);

    if (kv == qt) {
      int qrow0 = qt*64 + w*16;
#pragma unroll
      for (int ct = 0; ct < 4; ++ct)
#pragma unroll
        for (int r = 0; r < 4; ++r) {
          int col = kv*64 + ct*16 + l15;
          if (col > qrow0 + l4*4 + r) sc[ct][r] = -1e9f;
        }
    }

    float f[4];
#pragma unroll
    for (int r = 0; r < 4; ++r) {
      float mx = fmaxf(fmaxf(sc[0][r], sc[1][r]), fmaxf(sc[2][r], sc[3][r]));
      mx = fmaxf(mx, __shfl_xor(mx, 1));
      mx = fmaxf(mx, __shfl_xor(mx, 2));
      mx = fmaxf(mx, __shfl_xor(mx, 4));
      mx = fmaxf(mx, __shfl_xor(mx, 8));
      float nm = fmaxf(mrow[r], mx);
      f[r] = __expf(mrow[r] - nm);
      mrow[r] = nm;
    }
    float rs[4] = {0.f,0.f,0.f,0.f};
#pragma unroll
    for (int ct = 0; ct < 4; ++ct)
#pragma unroll
      for (int r = 0; r < 4; ++r) {
        float p = __expf(sc[ct][r] - mrow[r]);
        rs[r] += p;
        int row = l4*4 + r, col = ct*16 + l15;
        int byte = row*128 + (((col >> 3) ^ (row & 7)) << 4) + (col & 7)*2;
        *(u16*)(Pw + byte) = f2bf(p);
      }
#pragma unroll
    for (int r = 0; r < 4; ++r) {
      float sum = rs[r];
      sum += __shfl_xor(sum, 1);
      sum += __shfl_xor(sum, 2);
      sum += __shfl_xor(sum, 4);
      sum += __shfl_xor(sum, 8);
      lrow[r] = lrow[r]*f[r] + sum;
    }
#pragma unroll
    for (int n = 0; n < 8; ++n)
#pragma unroll
      for (int r = 0; r < 4; ++r) o[n][r] *= f[r];

    __builtin_amdgcn_s_setprio(1);
#pragma unroll
    for (int kk = 0; kk < 2; ++kk) {
      int pbyte = l15*128 + (((kk*4 + l4) ^ (l15 & 7)) << 4);
      bf16x8 pf = *(const bf16x8*)(Pw + pbyte);
#pragma unroll
      for (int n = 0; n < 8; ++n) {
        int vrow = n*16 + l15, s = kk*4 + l4;
        bf16x8 vf = *(const bf16x8*)(Vsb + vrow*128 + ((s ^ (vrow & 7)) << 4));
        o[n] = __builtin_amdgcn_mfma_f32_16x16x32_bf16(pf, vf, o[n], 0, 0, 0);
      }
    }
    __builtin_amdgcn_s_setprio(0);

    if (it == tA) {        // tile A complete: write out, reset, switch Q to tile B
#pragma unroll
      for (int n = 0; n < 8; ++n)
#pragma unroll
        for (int r = 0; r < 4; ++r) {
          int srow = tA*64 + w*16 + l4*4 + r;
          AOh[(size_t)srow * (H_*HD_) + n*16 + l15] = f2bf(o[n][r] / lrow[r]);
        }
#pragma unroll
      for (int n = 0; n < 8; ++n) o[n] = (f32x4){0.f,0.f,0.f,0.f};
#pragma unroll
      for (int r = 0; r < 4; ++r) { mrow[r] = -3e38f; lrow[r] = 0.f; }
#pragma unroll
      for (int kc = 0; kc < 4; ++kc)
        qf[kc] = *(const bf16x8*)(Qh + (size_t)(tB*64 + w*16 + l15)*HD_ + kc*32 + l4*8);
    }

    asm volatile("s_waitcnt vmcnt(0)" ::: "memory");
    __builtin_amdgcn_s_barrier();
    buf ^= 1;
  }
#undef ASTAGE

#pragma unroll
  for (int n = 0; n < 8; ++n)
#pragma unroll
    for (int r = 0; r < 4; ++r) {
      int srow = tB*64 + w*16 + l4*4 + r;
      AOh[(size_t)srow * (H_*HD_) + n*16 + l15] = f2bf(o[n][r] / lrow[r]);
    }
}

extern "C" void kernel_launch(void* const* d_in, const int* in_sizes, int n_in,
                              void* d_out, int out_size, void* d_ws, size_t ws_size,
                              hipStream_t stream) {
  (void)in_sizes; (void)n_in; (void)out_size; (void)ws_size;
  const float* x   = (const float*)d_in[0];
  const int*   sid = (const int*)  d_in[1];
  // d_in[2] = cache (dead), d_in[3] = mask (dead: causal re-derived)
  const float* Wq  = (const float*)d_in[4];
  const float* bq  = (const float*)d_in[5];
  const float* Wk  = (const float*)d_in[6];
  const float* bk  = (const float*)d_in[7];
  const float* Wv  = (const float*)d_in[8];
  const float* bv  = (const float*)d_in[9];
  const float* Wo  = (const float*)d_in[10];
  float* out = (float*)d_out;

  char* ws = (char*)d_ws;
  u16*   xb   = (u16*)  (ws);                    // 16 MB (aliased by AO later)
  u16*   WB   = (u16*)  (ws + 16777216);         // 48 MB  [6144][4096]
  u16*   WoT  = (u16*)  (ws + 67108864);         // 32 MB  [4096][4096]
  float* Cq   = (float*)(ws + 100663296);        // 48 MB  [2048][6144]
  u16*   qb   = (u16*)  (ws + 150994944);        // 16 MB  [B][H][S][HD]
  u16*   kb   = (u16*)  (ws + 167772160);        //  4 MB  [B][KVH][S][HD]
  u16*   vb   = (u16*)  (ws + 171966464);        //  4 MB
  u16*   VT   = (u16*)  (ws + 176160768);        //  4 MB  [B][KVH][HD][S]
  float* cosd = (float*)(ws + 180355072);        // 256 KB
  float* sind = (float*)(ws + 180617216);        // 256 KB (total ~181 MB)
  u16*   AO   = xb;                              // attention output reuses xb

  dim3 tb(32, 8);
  k_convert<<<8192, 256, 0, stream>>>(x, xb, (2048*4096)/4);
  k_transpose_w<<<dim3(128,128), tb, 0, stream>>>(Wq, WB, 4096, 4096);
  k_transpose_w<<<dim3( 32,128), tb, 0, stream>>>(Wk, WB + (size_t)4096*4096, 4096, 1024);
  k_transpose_w<<<dim3( 32,128), tb, 0, stream>>>(Wv, WB + (size_t)5120*4096, 4096, 1024);
  k_transpose_w<<<dim3(128,128), tb, 0, stream>>>(Wo, WoT, 4096, 4096);
  k_rope<<<256, 256, 0, stream>>>(sid, cosd, sind);
  k_gemm3<256><<<192, 512, 0, stream>>>(xb, WB, Cq, NQKV, 4096);
  k_pack<<<2048, 256, 0, stream>>>(Cq, bq, bk, bv, cosd, sind, qb, kb, vb);
  k_transpose_v<<<dim3(32,4,16), tb, 0, stream>>>(vb, VT);
  k_attn<<<512, 256, 0, stream>>>(qb, kb, VT, AO);
  k_gemm3<128><<<256, 512, 0, stream>>>(AO, WoT, out, 4096, 4096);
}

// Round 10
// 314.985 us; speedup vs baseline: 1.6411x; 1.0775x over previous
//
#include <hip/hip_runtime.h>
#include <hip/hip_bf16.h>

typedef unsigned short u16;
typedef unsigned int   u32;
using bf16x8 = __attribute__((ext_vector_type(8))) short;
using f32x4  = __attribute__((ext_vector_type(4))) float;

#define AS1 __attribute__((address_space(1)))
#define AS3 __attribute__((address_space(3)))

static constexpr int S_   = 1024;
static constexpr int D_   = 4096;
static constexpr int H_   = 32;
static constexpr int KVH_ = 8;
static constexpr int HD_  = 128;
static constexpr int NQKV = H_*HD_ + 2*KVH_*HD_;   // 6144

__device__ __forceinline__ u16 f2bf(float f) {
  union { float f; u32 u; } v; v.f = f;
  u32 r = v.u + 0x7FFFu + ((v.u >> 16) & 1u);      // RTNE
  return (u16)(r >> 16);
}

// ---------------- x f32 -> bf16 ----------------
__global__ void k_convert(const float* __restrict__ src, u16* __restrict__ dst, int n4) {
  int i = blockIdx.x * blockDim.x + threadIdx.x;
  if (i >= n4) return;
  float4 v = ((const float4*)src)[i];
  ushort4 o;
  o.x = f2bf(v.x); o.y = f2bf(v.y); o.z = f2bf(v.z); o.w = f2bf(v.w);
  ((ushort4*)dst)[i] = o;
}

// ---------------- W [K][N] f32 -> Wt [N][K] bf16 ----------------
__global__ void k_transpose_w(const float* __restrict__ src, u16* __restrict__ dst,
                              int K, int N) {
  __shared__ float t[32][33];
  int k0 = blockIdx.y * 32, n0 = blockIdx.x * 32;
  int tx = threadIdx.x, ty = threadIdx.y;           // (32,8)
#pragma unroll
  for (int i = 0; i < 4; ++i)
    t[ty + i*8][tx] = src[(size_t)(k0 + ty + i*8) * N + n0 + tx];
  __syncthreads();
#pragma unroll
  for (int i = 0; i < 4; ++i)
    dst[(size_t)(n0 + ty + i*8) * K + k0 + tx] = f2bf(t[tx][ty + i*8]);
}

// ---------------- V [BG][S][HD] bf16 -> Vt [BG][HD][S] bf16 ----------------
__global__ void k_transpose_v(const u16* __restrict__ src, u16* __restrict__ dst) {
  __shared__ u16 t[32][33];
  int bg = blockIdx.z;
  int s0 = blockIdx.x * 32, h0 = blockIdx.y * 32;
  src += (size_t)bg * S_ * HD_;
  dst += (size_t)bg * S_ * HD_;
  int tx = threadIdx.x, ty = threadIdx.y;
#pragma unroll
  for (int i = 0; i < 4; ++i)
    t[ty + i*8][tx] = src[(size_t)(s0 + ty + i*8) * HD_ + h0 + tx];
  __syncthreads();
#pragma unroll
  for (int i = 0; i < 4; ++i)
    dst[(size_t)(h0 + ty + i*8) * S_ + s0 + tx] = t[tx][ty + i*8];
}

// ---------------- RoPE tables: cos/sin [S][64] f32 ----------------
__global__ void k_rope(const int* __restrict__ sidx, float* __restrict__ cosd,
                       float* __restrict__ sind) {
  int i = blockIdx.x * blockDim.x + threadIdx.x;    // S*64
  int s = i >> 6, d = i & 63;
  float pos  = (float)sidx[s];
  float invf = expf(-0.21586735246819178f * (float)d);  // 1e6^(-d/64)
  float ph   = pos * invf;
  cosd[i] = cosf(ph);
  sind[i] = sinf(ph);
}

// ==== QKV GEMM (M=2048, N=6144, K=4096) with fused bias+RoPE+pack epilogue ====
// 512 thr = 8 waves in 4M x 2N grid: wave = 64 rows x 128 cols (one full head) so the
// RoPE partner (d, d+64) = fragments (j, j+4) of the SAME lane. Epilogue writes
// qb/kb/vb bf16 directly (block-uniform Q/K/V branch; BN=256 divides the sections).
// Staging: strict 2-ahead — iter kt stages ONLY tile kt+2 (B at ph2, A at ph3 into
// slots freed by ph1/ph2 lgkm drains); vmcnt(8) at ph3 = oldest 8 = tile kt+1 landed.
__global__ __launch_bounds__(512, 2) void k_gemmq(
    const u16* __restrict__ A, const u16* __restrict__ Bt,
    const float* __restrict__ bq, const float* __restrict__ bk,
    const float* __restrict__ bv,
    const float* __restrict__ cosd, const float* __restrict__ sind,
    u16* __restrict__ qb, u16* __restrict__ kb, u16* __restrict__ vb)
{
  constexpr int K = 4096;
  constexpr int ABYT = 256*128, BBYT = 256*128, STEP = ABYT+BBYT;
  __shared__ __align__(16) char lds[2*STEP];       // 128 KB

  const int cpx = (int)gridDim.x >> 3;             // 24
  const int wkid = ((int)blockIdx.x & 7)*cpx + ((int)blockIdx.x >> 3);
  const int NT = 24;
  const int m0 = (wkid / NT) * 256, n0 = (wkid % NT) * 256;
  const int tid = threadIdx.x, w = tid>>6, lane = tid&63;
  const int l15 = lane&15, l4 = lane>>4;
  const int wr = w>>1, wc = w&1;                   // 4M x 2N
  const int row0 = tid>>3;
  const int ss = (tid&7) ^ (row0&7);
  const int NK = K >> 6;                           // 64

  f32x4 acc[4][8];
#pragma unroll
  for (int i = 0; i < 4; ++i)
#pragma unroll
    for (int j = 0; j < 8; ++j) acc[i][j] = (f32x4){0.f,0.f,0.f,0.f};

  bf16x8 af[2][2];
  bf16x8 bfr[2][4][2];

#define QCHUNK(kt_, part_, r0c_)                                              \
  __builtin_amdgcn_global_load_lds(                                           \
    (AS1 void*)(((part_) ? Bt + (size_t)(n0 + (r0c_) + row0)*K                \
                         : A  + (size_t)(m0 + (r0c_) + row0)*K)               \
                + (size_t)(kt_)*64 + ss*8),                                   \
    (AS3 void*)(lds + ((kt_)&1)*STEP + (part_)*ABYT + (r0c_)*128 + w*1024),   \
    16, 0, 0)

#define QLOAD_A(mh_)                                                          \
  _Pragma("unroll") for (int i2 = 0; i2 < 2; ++i2)                            \
  _Pragma("unroll") for (int kk = 0; kk < 2; ++kk) {                          \
    int row = wr*64 + ((mh_)*2 + i2)*16 + l15;                                \
    af[i2][kk] = *(const bf16x8*)(lA + row*128 + (((kk*4+l4) ^ (row&7)) << 4)); }

#define QLOAD_B(nh_)                                                          \
  _Pragma("unroll") for (int jj = 0; jj < 4; ++jj)                            \
  _Pragma("unroll") for (int kk = 0; kk < 2; ++kk) {                          \
    int row = wc*128 + ((nh_)*4 + jj)*16 + l15;                               \
    bfr[nh_][jj][kk] = *(const bf16x8*)(lB + row*128 + (((kk*4+l4) ^ (row&7)) << 4)); }

#define QMFMA(mh_, nh_)                                                       \
  __builtin_amdgcn_s_setprio(1);                                              \
  _Pragma("unroll") for (int i2 = 0; i2 < 2; ++i2)                            \
  _Pragma("unroll") for (int jj = 0; jj < 4; ++jj)                            \
  _Pragma("unroll") for (int kk = 0; kk < 2; ++kk)                            \
    acc[(mh_)*2+i2][(nh_)*4+jj] = __builtin_amdgcn_mfma_f32_16x16x32_bf16(    \
        af[i2][kk], bfr[nh_][jj][kk], acc[(mh_)*2+i2][(nh_)*4+jj], 0, 0, 0);  \
  __builtin_amdgcn_s_setprio(0);

#define BAR   __builtin_amdgcn_s_barrier()
#define SCHB  __builtin_amdgcn_sched_barrier(0)
#define WLGKM asm volatile("s_waitcnt lgkmcnt(0)" ::: "memory")

  // prologue: tiles 0 and 1 in full (16 loads); wait oldest 8 (tile 0)
  QCHUNK(0,0,0); QCHUNK(0,0,64); QCHUNK(0,0,128); QCHUNK(0,0,192);
  QCHUNK(0,1,0); QCHUNK(0,1,64); QCHUNK(0,1,128); QCHUNK(0,1,192);
  QCHUNK(1,0,0); QCHUNK(1,0,64); QCHUNK(1,0,128); QCHUNK(1,0,192);
  QCHUNK(1,1,0); QCHUNK(1,1,64); QCHUNK(1,1,128); QCHUNK(1,1,192);
  asm volatile("s_waitcnt vmcnt(8)" ::: "memory");
  BAR; SCHB;

  for (int kt = 0; kt < NK; ++kt) {
    const char* lA = lds + (kt&1)*STEP;
    const char* lB = lA + ABYT;
    // ph0: quadrant (0,0)
    QLOAD_A(0); QLOAD_B(0);
    BAR; WLGKM; SCHB;
    QMFMA(0,0);
    BAR;
    // ph1: quadrant (0,1)
    QLOAD_B(1);
    BAR; WLGKM; SCHB;
    QMFMA(0,1);
    BAR;
    // ph2: quadrant (1,0); stage B(kt+2) into current-buf B slots (dead since ph1)
    QLOAD_A(1);
    if (kt+2 < NK) { QCHUNK(kt+2,1,0); QCHUNK(kt+2,1,64); QCHUNK(kt+2,1,128); QCHUNK(kt+2,1,192); }
    BAR; WLGKM; SCHB;
    QMFMA(1,0);
    BAR;
    // ph3: quadrant (1,1); stage A(kt+2) into current-buf A slots (dead since ph2)
    if (kt+2 < NK) {
      QCHUNK(kt+2,0,0); QCHUNK(kt+2,0,64); QCHUNK(kt+2,0,128); QCHUNK(kt+2,0,192);
      asm volatile("s_waitcnt vmcnt(8)" ::: "memory");   // oldest 8 = tile kt+1
    } else {
      asm volatile("s_waitcnt vmcnt(0)" ::: "memory");
    }
    BAR; WLGKM; SCHB;
    QMFMA(1,1);
    BAR;
  }
#undef QCHUNK
#undef QLOAD_A
#undef QLOAD_B
#undef QMFMA

  // ---- fused epilogue: bias + RoPE(+scale) + bf16 pack ----
  const int btype = (n0 >= H_*HD_) + (n0 >= H_*HD_ + KVH_*HD_);  // 0=Q 1=K 2=V
  const int colbase = n0 + wc*128 - (btype==1 ? H_*HD_ : btype==2 ? H_*HD_+KVH_*HD_ : 0);
  const int hloc = colbase >> 7;
  const float* bias = btype==0 ? bq : btype==1 ? bk : bv;
  u16* dst = btype==0 ? qb : btype==1 ? kb : vb;
  const int nheads = btype==0 ? H_ : KVH_;
  const float scale = btype==0 ? 0.08838834764831845f : 1.0f;

  float bb[8];
#pragma unroll
  for (int j = 0; j < 8; ++j) bb[j] = bias[colbase + j*16 + l15];

#pragma unroll
  for (int i = 0; i < 4; ++i)
#pragma unroll
    for (int r = 0; r < 4; ++r) {
      int sr = m0 + wr*64 + i*16 + l4*4 + r;
      int b_ = sr >> 10, s_ = sr & 1023;
      size_t obase = (((size_t)b_*nheads + hloc)*S_ + s_)*(size_t)HD_;
      if (btype < 2) {
#pragma unroll
        for (int j = 0; j < 4; ++j) {
          float cs = cosd[s_*64 + j*16 + l15];
          float sn = sind[s_*64 + j*16 + l15];
          float lo = acc[i][j][r]   + bb[j];
          float hi = acc[i][j+4][r] + bb[j+4];
          dst[obase + j*16 + l15]      = f2bf((lo*cs - hi*sn) * scale);
          dst[obase + 64 + j*16 + l15] = f2bf((hi*cs + lo*sn) * scale);
        }
      } else {
#pragma unroll
        for (int j = 0; j < 8; ++j)
          dst[obase + j*16 + l15] = f2bf(acc[i][j][r] + bb[j]);
      }
    }
}

// ---- 256xBN bf16 GEMM, 8-phase counted-vmcnt pipeline (out-projection) ----
template<int BN>
__global__ __launch_bounds__(512, 2) void k_gemm3(
    const u16* __restrict__ A, const u16* __restrict__ Bt,
    float* __restrict__ C, int N, int K)
{
  constexpr int WN = BN/4, NJ = WN/16, NH = NJ/2;
  constexpr int ABYT = 256*128, BBYT = BN*128, STEP = ABYT+BBYT;
  __shared__ __align__(16) char lds[2*STEP];

  const int cpx = (int)gridDim.x >> 3;
  const int wkid = ((int)blockIdx.x & 7)*cpx + ((int)blockIdx.x >> 3);
  const int NT = N / BN;
  const int m0 = (wkid / NT) * 256, n0 = (wkid % NT) * BN;
  const int tid = threadIdx.x, w = tid>>6, lane = tid&63;
  const int l15 = lane&15, l4 = lane>>4;
  const int wr = w>>2, wc = w&3;
  const int row0 = tid>>3;
  const int ss = (tid&7) ^ (row0&7);
  const int NK = K >> 6;

  f32x4 acc[8][NJ];
#pragma unroll
  for (int i = 0; i < 8; ++i)
#pragma unroll
    for (int j = 0; j < NJ; ++j) acc[i][j] = (f32x4){0.f,0.f,0.f,0.f};

  bf16x8 af[4][2];
  bf16x8 bf[2][NH][2];

#define CHUNK(kt_, part_, r0c_)                                               \
  __builtin_amdgcn_global_load_lds(                                           \
    (AS1 void*)(((part_) ? Bt + (size_t)(n0 + (r0c_) + row0)*K                \
                         : A  + (size_t)(m0 + (r0c_) + row0)*K)               \
                + (size_t)(kt_)*64 + ss*8),                                   \
    (AS3 void*)(lds + ((kt_)&1)*STEP + (part_)*ABYT + (r0c_)*128 + w*1024),   \
    16, 0, 0)

#define LOAD_A(mh_)                                                           \
  _Pragma("unroll") for (int i = 0; i < 4; ++i)                               \
  _Pragma("unroll") for (int kk = 0; kk < 2; ++kk) {                          \
    int row = wr*128 + (mh_)*64 + i*16 + l15;                                 \
    af[i][kk] = *(const bf16x8*)(lA + row*128 + (((kk*4+l4) ^ (row&7)) << 4)); }

#define LOAD_B(nh_)                                                           \
  _Pragma("unroll") for (int jj = 0; jj < NH; ++jj)                           \
  _Pragma("unroll") for (int kk = 0; kk < 2; ++kk) {                          \
    int row = wc*WN + ((nh_)*NH + jj)*16 + l15;                               \
    bf[nh_][jj][kk] = *(const bf16x8*)(lB + row*128 + (((kk*4+l4) ^ (row&7)) << 4)); }

#define MFMA_PH(mh_, nh_)                                                     \
  __builtin_amdgcn_s_setprio(1);                                              \
  _Pragma("unroll") for (int i = 0; i < 4; ++i)                               \
  _Pragma("unroll") for (int jj = 0; jj < NH; ++jj)                           \
  _Pragma("unroll") for (int kk = 0; kk < 2; ++kk)                            \
    acc[(mh_)*4+i][(nh_)*NH+jj] = __builtin_amdgcn_mfma_f32_16x16x32_bf16(    \
        af[i][kk], bf[nh_][jj][kk], acc[(mh_)*4+i][(nh_)*NH+jj], 0, 0, 0);    \
  __builtin_amdgcn_s_setprio(0);

  CHUNK(0,0,0); CHUNK(0,0,64); CHUNK(0,0,128); CHUNK(0,0,192);
  CHUNK(0,1,0); CHUNK(0,1,64);
  if constexpr (BN == 256) { CHUNK(0,1,128); CHUNK(0,1,192); }
  CHUNK(1,0,0); CHUNK(1,0,128);
  asm volatile("s_waitcnt vmcnt(2)" ::: "memory");
  BAR; SCHB;

  for (int kt = 0; kt < NK; ++kt) {
    const char* lA = lds + (kt&1)*STEP;
    const char* lB = lA + ABYT;
    LOAD_A(0); LOAD_B(0);
    if (kt+1 < NK) { CHUNK(kt+1,0,64); CHUNK(kt+1,0,192); }
    BAR; WLGKM; SCHB;
    MFMA_PH(0,0);
    BAR;
    LOAD_B(1);
    if (kt+1 < NK) {
      CHUNK(kt+1,1,0); CHUNK(kt+1,1,64);
      if constexpr (BN == 256) { CHUNK(kt+1,1,128); CHUNK(kt+1,1,192); }
    }
    BAR; WLGKM; SCHB;
    MFMA_PH(0,1);
    BAR;
    LOAD_A(1);
    if (kt+2 < NK) { CHUNK(kt+2,0,0); CHUNK(kt+2,0,128); }
    BAR; WLGKM; SCHB;
    MFMA_PH(1,0);
    BAR;
    if (kt+2 < NK) asm volatile("s_waitcnt vmcnt(2)" ::: "memory");
    else           asm volatile("s_waitcnt vmcnt(0)" ::: "memory");
    BAR; WLGKM; SCHB;
    MFMA_PH(1,1);
    BAR;
  }
#undef CHUNK
#undef LOAD_A
#undef LOAD_B
#undef MFMA_PH

#pragma unroll
  for (int i = 0; i < 8; ++i)
#pragma unroll
    for (int j = 0; j < NJ; ++j) {
      int r0 = m0 + wr*128 + i*16 + l4*4;
      int c0 = n0 + wc*WN + j*16 + l15;
#pragma unroll
      for (int r = 0; r < 4; ++r)
        C[(size_t)(r0 + r) * N + c0] = acc[i][j][r];
    }
}

// ---------------- causal GQA flash attention: block-cooperative LDS-staged K/V -------
__global__ __launch_bounds__(256, 4) void k_attn(
    const u16* __restrict__ Q, const u16* __restrict__ Kc,
    const u16* __restrict__ Vt, const u16* __restrict__ AOdummy, u16* __restrict__ AO)
{
  __shared__ __align__(16) char Kls[2][16384];
  __shared__ __align__(16) char Vls[2][16384];
  __shared__ u16 Pl[4][1024];

  int id = blockIdx.x;
  int slot = id >> 3;
  int bg   = (id & 7)*2 + (slot & 1);
  int rem  = slot >> 1;
  int h_in = rem & 3, bx = rem >> 2;
  int b = bg >> 3, g = bg & 7, h = g*4 + h_in;
  int tA = bx, tB = 15 - bx;

  int tid = threadIdx.x, w = tid >> 6, lane = tid & 63;
  int l15 = lane & 15, l4 = lane >> 4;
  const u16* Qh = Q  + ((size_t)b*H_   + h) * S_ * HD_;
  const u16* Kp = Kc + ((size_t)b*KVH_ + g) * S_ * HD_;
  const u16* Vp = Vt + ((size_t)b*KVH_ + g) * (size_t)HD_ * S_;
  u16* AOh = AO + ((size_t)b*S_) * (H_*HD_) + h*HD_;
  char* Pw = (char*)&Pl[w][0];

  int kOff[4], vOff[4];
#pragma unroll
  for (int c = 0; c < 4; ++c) {
    int ci = c*256 + tid;
    int krow = ci >> 4, ks = ci & 15;
    kOff[c] = krow * HD_ + ((ks & 8) | ((ks & 7) ^ (krow & 7))) * 8;
    int vrow = ci >> 3, vs = ci & 7;
    vOff[c] = vrow * S_ + (vs ^ (vrow & 7)) * 8;
  }

#define ASTAGE(kv_, bb_) {                                                    \
    const u16* ks_ = Kp + (size_t)(kv_) * 64 * HD_;                           \
    const u16* vs_ = Vp + (size_t)(kv_) * 64;                                 \
    _Pragma("unroll") for (int c = 0; c < 4; ++c) {                           \
      __builtin_amdgcn_global_load_lds((AS1 void*)(ks_ + kOff[c]),            \
          (AS3 void*)(&Kls[bb_][0] + c*4096 + w*1024), 16, 0, 0);             \
      __builtin_amdgcn_global_load_lds((AS1 void*)(vs_ + vOff[c]),            \
          (AS3 void*)(&Vls[bb_][0] + c*4096 + w*1024), 16, 0, 0); } }

  bf16x8 qf[4];
#pragma unroll
  for (int kc = 0; kc < 4; ++kc)
    qf[kc] = *(const bf16x8*)(Qh + (size_t)(tA*64 + w*16 + l15)*HD_ + kc*32 + l4*8);

  f32x4 o[8];
#pragma unroll
  for (int n = 0; n < 8; ++n) o[n] = (f32x4){0.f,0.f,0.f,0.f};
  float mrow[4] = {-3e38f,-3e38f,-3e38f,-3e38f};
  float lrow[4] = {0.f,0.f,0.f,0.f};

  ASTAGE(0, 0);
  asm volatile("s_waitcnt vmcnt(0)" ::: "memory");
  __builtin_amdgcn_s_barrier();

  const int NIT = tA + tB + 2;
  int buf = 0;
  for (int it = 0; it < NIT; ++it) {
    bool phA = (it <= tA);
    int kv = phA ? it : it - tA - 1;
    int qt = phA ? tA : tB;
    if (it + 1 < NIT) {
      int kvn = (it + 1 <= tA) ? it + 1 : it - tA;
      ASTAGE(kvn, buf ^ 1);
    }
    const char* Ksb = &Kls[buf][0];
    const char* Vsb = &Vls[buf][0];

    f32x4 sc[4];
    __builtin_amdgcn_s_setprio(1);
#pragma unroll
    for (int ct = 0; ct < 4; ++ct) {
      f32x4 s4 = (f32x4){0.f,0.f,0.f,0.f};
#pragma unroll
      for (int kc = 0; kc < 4; ++kc) {
        int row = ct*16 + l15, s = kc*4 + l4;
        bf16x8 kf = *(const bf16x8*)(Ksb + row*256 + ((((s & 7) ^ (row & 7)) | (s & 8)) << 4));
        s4 = __builtin_amdgcn_mfma_f32_16x16x32_bf16(qf[kc], kf, s4, 0, 0, 0);
      }
      sc[ct] = s4;
    }
    __builtin_amdgcn_s_setprio(0);

    if (kv == qt) {
      int qrow0 = qt*64 + w*16;
#pragma unroll
      for (int ct = 0; ct < 4; ++ct)
#pragma unroll
        for (int r = 0; r < 4; ++r) {
          int col = kv*64 + ct*16 + l15;
          if (col > qrow0 + l4*4 + r) sc[ct][r] = -1e9f;
        }
    }

    float f[4];
#pragma unroll
    for (int r = 0; r < 4; ++r) {
      float mx = fmaxf(fmaxf(sc[0][r], sc[1][r]), fmaxf(sc[2][r], sc[3][r]));
      mx = fmaxf(mx, __shfl_xor(mx, 1));
      mx = fmaxf(mx, __shfl_xor(mx, 2));
      mx = fmaxf(mx, __shfl_xor(mx, 4));
      mx = fmaxf(mx, __shfl_xor(mx, 8));
      float nm = fmaxf(mrow[r], mx);
      f[r] = __expf(mrow[r] - nm);
      mrow[r] = nm;
    }
    float rs[4] = {0.f,0.f,0.f,0.f};
#pragma unroll
    for (int ct = 0; ct < 4; ++ct)
#pragma unroll
      for (int r = 0; r < 4; ++r) {
        float p = __expf(sc[ct][r] - mrow[r]);
        rs[r] += p;
        int row = l4*4 + r, col = ct*16 + l15;
        int byte = row*128 + (((col >> 3) ^ (row & 7)) << 4) + (col & 7)*2;
        *(u16*)(Pw + byte) = f2bf(p);
      }
#pragma unroll
    for (int r = 0; r < 4; ++r) {
      float sum = rs[r];
      sum += __shfl_xor(sum, 1);
      sum += __shfl_xor(sum, 2);
      sum += __shfl_xor(sum, 4);
      sum += __shfl_xor(sum, 8);
      lrow[r] = lrow[r]*f[r] + sum;
    }
#pragma unroll
    for (int n = 0; n < 8; ++n)
#pragma unroll
      for (int r = 0; r < 4; ++r) o[n][r] *= f[r];

    __builtin_amdgcn_s_setprio(1);
#pragma unroll
    for (int kk = 0; kk < 2; ++kk) {
      int pbyte = l15*128 + (((kk*4 + l4) ^ (l15 & 7)) << 4);
      bf16x8 pf = *(const bf16x8*)(Pw + pbyte);
#pragma unroll
      for (int n = 0; n < 8; ++n) {
        int vrow = n*16 + l15, s = kk*4 + l4;
        bf16x8 vf = *(const bf16x8*)(Vsb + vrow*128 + ((s ^ (vrow & 7)) << 4));
        o[n] = __builtin_amdgcn_mfma_f32_16x16x32_bf16(pf, vf, o[n], 0, 0, 0);
      }
    }
    __builtin_amdgcn_s_setprio(0);

    if (it == tA) {
#pragma unroll
      for (int n = 0; n < 8; ++n)
#pragma unroll
        for (int r = 0; r < 4; ++r) {
          int srow = tA*64 + w*16 + l4*4 + r;
          AOh[(size_t)srow * (H_*HD_) + n*16 + l15] = f2bf(o[n][r] / lrow[r]);
        }
#pragma unroll
      for (int n = 0; n < 8; ++n) o[n] = (f32x4){0.f,0.f,0.f,0.f};
#pragma unroll
      for (int r = 0; r < 4; ++r) { mrow[r] = -3e38f; lrow[r] = 0.f; }
#pragma unroll
      for (int kc = 0; kc < 4; ++kc)
        qf[kc] = *(const bf16x8*)(Qh + (size_t)(tB*64 + w*16 + l15)*HD_ + kc*32 + l4*8);
    }

    asm volatile("s_waitcnt vmcnt(0)" ::: "memory");
    __builtin_amdgcn_s_barrier();
    buf ^= 1;
  }
#undef ASTAGE

#pragma unroll
  for (int n = 0; n < 8; ++n)
#pragma unroll
    for (int r = 0; r < 4; ++r) {
      int srow = tB*64 + w*16 + l4*4 + r;
      AOh[(size_t)srow * (H_*HD_) + n*16 + l15] = f2bf(o[n][r] / lrow[r]);
    }
}

extern "C" void kernel_launch(void* const* d_in, const int* in_sizes, int n_in,
                              void* d_out, int out_size, void* d_ws, size_t ws_size,
                              hipStream_t stream) {
  (void)in_sizes; (void)n_in; (void)out_size; (void)ws_size;
  const float* x   = (const float*)d_in[0];
  const int*   sid = (const int*)  d_in[1];
  // d_in[2] = cache (dead), d_in[3] = mask (dead: causal re-derived)
  const float* Wq  = (const float*)d_in[4];
  const float* bq  = (const float*)d_in[5];
  const float* Wk  = (const float*)d_in[6];
  const float* bk  = (const float*)d_in[7];
  const float* Wv  = (const float*)d_in[8];
  const float* bv  = (const float*)d_in[9];
  const float* Wo  = (const float*)d_in[10];
  float* out = (float*)d_out;

  char* ws = (char*)d_ws;
  u16*   xb   = (u16*)  (ws);                    // 16 MB (aliased by AO later)
  u16*   WB   = (u16*)  (ws + 16777216);         // 48 MB  [6144][4096]
  u16*   WoT  = (u16*)  (ws + 67108864);         // 32 MB  [4096][4096]
  u16*   qb   = (u16*)  (ws + 150994944);        // 16 MB  [B][H][S][HD]
  u16*   kb   = (u16*)  (ws + 167772160);        //  4 MB  [B][KVH][S][HD]
  u16*   vb   = (u16*)  (ws + 171966464);        //  4 MB
  u16*   VT   = (u16*)  (ws + 176160768);        //  4 MB  [B][KVH][HD][S]
  float* cosd = (float*)(ws + 180355072);        // 256 KB
  float* sind = (float*)(ws + 180617216);        // 256 KB
  u16*   AO   = xb;                              // attention output reuses xb

  dim3 tb(32, 8);
  k_convert<<<8192, 256, 0, stream>>>(x, xb, (2048*4096)/4);
  k_transpose_w<<<dim3(128,128), tb, 0, stream>>>(Wq, WB, 4096, 4096);
  k_transpose_w<<<dim3( 32,128), tb, 0, stream>>>(Wk, WB + (size_t)4096*4096, 4096, 1024);
  k_transpose_w<<<dim3( 32,128), tb, 0, stream>>>(Wv, WB + (size_t)5120*4096, 4096, 1024);
  k_transpose_w<<<dim3(128,128), tb, 0, stream>>>(Wo, WoT, 4096, 4096);
  k_rope<<<256, 256, 0, stream>>>(sid, cosd, sind);
  k_gemmq<<<192, 512, 0, stream>>>(xb, WB, bq, bk, bv, cosd, sind, qb, kb, vb);
  k_transpose_v<<<dim3(32,4,16), tb, 0, stream>>>(vb, VT);
  k_attn<<<512, 256, 0, stream>>>(qb, kb, VT, qb, AO);
  k_gemm3<128><<<256, 512, 0, stream>>>(AO, WoT, out, 4096, 4096);
}

// Round 12
// 294.036 us; speedup vs baseline: 1.7580x; 1.0712x over previous
//
#include <hip/hip_runtime.h>
#include <hip/hip_bf16.h>

typedef unsigned short u16;
typedef unsigned int   u32;
using bf16x8 = __attribute__((ext_vector_type(8))) short;
using f32x4  = __attribute__((ext_vector_type(4))) float;

#define AS1 __attribute__((address_space(1)))
#define AS3 __attribute__((address_space(3)))

static constexpr int S_   = 1024;
static constexpr int D_   = 4096;
static constexpr int H_   = 32;
static constexpr int KVH_ = 8;
static constexpr int HD_  = 128;
static constexpr int NQKV = H_*HD_ + 2*KVH_*HD_;   // 6144

__device__ __forceinline__ u16 f2bf(float f) {
  union { float f; u32 u; } v; v.f = f;
  u32 r = v.u + 0x7FFFu + ((v.u >> 16) & 1u);      // RTNE
  return (u16)(r >> 16);
}

// ---------------- x f32 -> bf16 ----------------
__global__ void k_convert(const float* __restrict__ src, u16* __restrict__ dst, int n4) {
  int i = blockIdx.x * blockDim.x + threadIdx.x;
  if (i >= n4) return;
  float4 v = ((const float4*)src)[i];
  ushort4 o;
  o.x = f2bf(v.x); o.y = f2bf(v.y); o.z = f2bf(v.z); o.w = f2bf(v.w);
  ((ushort4*)dst)[i] = o;
}

// ---------------- W [K][N] f32 -> Wt [N][K] bf16 ----------------
__global__ void k_transpose_w(const float* __restrict__ src, u16* __restrict__ dst,
                              int K, int N) {
  __shared__ float t[32][33];
  int k0 = blockIdx.y * 32, n0 = blockIdx.x * 32;
  int tx = threadIdx.x, ty = threadIdx.y;           // (32,8)
#pragma unroll
  for (int i = 0; i < 4; ++i)
    t[ty + i*8][tx] = src[(size_t)(k0 + ty + i*8) * N + n0 + tx];
  __syncthreads();
#pragma unroll
  for (int i = 0; i < 4; ++i)
    dst[(size_t)(n0 + ty + i*8) * K + k0 + tx] = f2bf(t[tx][ty + i*8]);
}

// ---------------- V [BG][S][HD] bf16 -> Vt [BG][HD][S] bf16 ----------------
__global__ void k_transpose_v(const u16* __restrict__ src, u16* __restrict__ dst) {
  __shared__ u16 t[32][33];
  int bg = blockIdx.z;
  int s0 = blockIdx.x * 32, h0 = blockIdx.y * 32;
  src += (size_t)bg * S_ * HD_;
  dst += (size_t)bg * S_ * HD_;
  int tx = threadIdx.x, ty = threadIdx.y;
#pragma unroll
  for (int i = 0; i < 4; ++i)
    t[ty + i*8][tx] = src[(size_t)(s0 + ty + i*8) * HD_ + h0 + tx];
  __syncthreads();
#pragma unroll
  for (int i = 0; i < 4; ++i)
    dst[(size_t)(h0 + ty + i*8) * S_ + s0 + tx] = t[tx][ty + i*8];
}

// ---------------- RoPE tables: cos/sin [S][64] f32 ----------------
__global__ void k_rope(const int* __restrict__ sidx, float* __restrict__ cosd,
                       float* __restrict__ sind) {
  int i = blockIdx.x * blockDim.x + threadIdx.x;    // S*64
  int s = i >> 6, d = i & 63;
  float pos  = (float)sidx[s];
  float invf = expf(-0.21586735246819178f * (float)d);  // 1e6^(-d/64)
  float ph   = pos * invf;
  cosd[i] = cosf(ph);
  sind[i] = sinf(ph);
}

#define BAR   __builtin_amdgcn_s_barrier()
#define SCHB  __builtin_amdgcn_sched_barrier(0)

// ==== QKV GEMM (M=2048, N=6144, K=4096), reg-pipelined counted-lgkm schedule ====
// 512 thr = 8 waves, 4M x 2N (wave = 64 rows x 128 cols = one head: RoPE in-register).
// Per K-tile: ph0{issue B1, lgkm(8), MFMA00} ph1{issue A1, lgkm(4), BAR, gloadB(t+2),
// MFMA01} ph2{lgkm(0), BAR, gloadA(t+2), MFMA10} ph3{vmcnt(8), BAR, read A0B0(t+1),
// MFMA11}. ds_reads drain under MFMA; 3 barriers/tile; vmcnt never 0 in steady state.
__global__ __launch_bounds__(512, 2) void k_gemmq(
    const u16* __restrict__ A, const u16* __restrict__ Bt,
    const float* __restrict__ bq, const float* __restrict__ bk,
    const float* __restrict__ bv,
    const float* __restrict__ cosd, const float* __restrict__ sind,
    u16* __restrict__ qb, u16* __restrict__ kb, u16* __restrict__ vb)
{
  constexpr int K = 4096;
  constexpr int ABYT = 256*128, BBYT = 256*128, STEP = ABYT+BBYT;
  __shared__ __align__(16) char lds[2*STEP];       // 128 KB

  const int cpx = (int)gridDim.x >> 3;             // 24
  const int wkid = ((int)blockIdx.x & 7)*cpx + ((int)blockIdx.x >> 3);
  const int NT = 24;
  const int m0 = (wkid / NT) * 256, n0 = (wkid % NT) * 256;
  const int tid = threadIdx.x, w = tid>>6, lane = tid&63;
  const int l15 = lane&15, l4 = lane>>4;
  const int wr = w>>1, wc = w&1;                   // 4M x 2N
  const int row0 = tid>>3;
  const int ss = (tid&7) ^ (row0&7);
  const int NK = K >> 6;                           // 64

  f32x4 acc[4][8];
#pragma unroll
  for (int i = 0; i < 4; ++i)
#pragma unroll
    for (int j = 0; j < 8; ++j) acc[i][j] = (f32x4){0.f,0.f,0.f,0.f};

  bf16x8 af[2][2][2];    // [half][i2][kk] — both halves live (pipelined)
  bf16x8 bfr[2][4][2];   // [half][jj][kk]

#define QCHUNK(kt_, part_, r0c_)                                              \
  __builtin_amdgcn_global_load_lds(                                           \
    (AS1 void*)(((part_) ? Bt + (size_t)(n0 + (r0c_) + row0)*K                \
                         : A  + (size_t)(m0 + (r0c_) + row0)*K)               \
                + (size_t)(kt_)*64 + ss*8),                                   \
    (AS3 void*)(lds + ((kt_)&1)*STEP + (part_)*ABYT + (r0c_)*128 + w*1024),   \
    16, 0, 0)

#define QR_A(mh_, lA_)                                                        \
  _Pragma("unroll") for (int i2 = 0; i2 < 2; ++i2)                            \
  _Pragma("unroll") for (int kk = 0; kk < 2; ++kk) {                          \
    int row = wr*64 + ((mh_)*2 + i2)*16 + l15;                                \
    af[mh_][i2][kk] = *(const bf16x8*)((lA_) + row*128 + (((kk*4+l4) ^ (row&7)) << 4)); }

#define QR_B(nh_, lB_)                                                        \
  _Pragma("unroll") for (int jj = 0; jj < 4; ++jj)                            \
  _Pragma("unroll") for (int kk = 0; kk < 2; ++kk) {                          \
    int row = wc*128 + ((nh_)*4 + jj)*16 + l15;                               \
    bfr[nh_][jj][kk] = *(const bf16x8*)((lB_) + row*128 + (((kk*4+l4) ^ (row&7)) << 4)); }

#define QMFMA(mh_, nh_)                                                       \
  __builtin_amdgcn_s_setprio(1);                                              \
  _Pragma("unroll") for (int i2 = 0; i2 < 2; ++i2)                            \
  _Pragma("unroll") for (int jj = 0; jj < 4; ++jj)                            \
  _Pragma("unroll") for (int kk = 0; kk < 2; ++kk)                            \
    acc[(mh_)*2+i2][(nh_)*4+jj] = __builtin_amdgcn_mfma_f32_16x16x32_bf16(    \
        af[mh_][i2][kk], bfr[nh_][jj][kk], acc[(mh_)*2+i2][(nh_)*4+jj], 0, 0, 0); \
  __builtin_amdgcn_s_setprio(0);

  // prologue: stage tiles 0,1; wait tile0; read its A0,B0 (12 reads left in flight)
  QCHUNK(0,0,0); QCHUNK(0,0,64); QCHUNK(0,0,128); QCHUNK(0,0,192);
  QCHUNK(0,1,0); QCHUNK(0,1,64); QCHUNK(0,1,128); QCHUNK(0,1,192);
  QCHUNK(1,0,0); QCHUNK(1,0,64); QCHUNK(1,0,128); QCHUNK(1,0,192);
  QCHUNK(1,1,0); QCHUNK(1,1,64); QCHUNK(1,1,128); QCHUNK(1,1,192);
  asm volatile("s_waitcnt vmcnt(8)" ::: "memory");
  BAR; SCHB;
  {
    const char* lA0 = lds;
    const char* lB0 = lds + ABYT;
    QR_A(0, lA0); QR_B(0, lB0);
  }

  for (int kt = 0; kt < NK; ++kt) {
    const char* lA = lds + (kt&1)*STEP;
    const char* lB = lA + ABYT;
    // ph0: issue B1(8); drain A0,B0; MFMA(0,0)
    QR_B(1, lB);
    asm volatile("s_waitcnt lgkmcnt(8)" ::: "memory");
    SCHB;
    QMFMA(0,0);
    // ph1: issue A1(4); drain B1; barrier; stage B(kt+2); MFMA(0,1)
    QR_A(1, lA);
    asm volatile("s_waitcnt lgkmcnt(4)" ::: "memory");
    BAR; SCHB;
    if (kt+2 < NK) { QCHUNK(kt+2,1,0); QCHUNK(kt+2,1,64); QCHUNK(kt+2,1,128); QCHUNK(kt+2,1,192); }
    QMFMA(0,1);
    // ph2: drain A1; barrier; stage A(kt+2); MFMA(1,0)
    asm volatile("s_waitcnt lgkmcnt(0)" ::: "memory");
    BAR; SCHB;
    if (kt+2 < NK) { QCHUNK(kt+2,0,0); QCHUNK(kt+2,0,64); QCHUNK(kt+2,0,128); QCHUNK(kt+2,0,192); }
    QMFMA(1,0);
    // ph3: tile kt+1 resident; barrier; read its A0,B0 (fly under MFMA); MFMA(1,1)
    if (kt+1 < NK) {
      if (kt+2 < NK) asm volatile("s_waitcnt vmcnt(8)" ::: "memory");
      else           asm volatile("s_waitcnt vmcnt(0)" ::: "memory");
      BAR; SCHB;
      const char* lAn = lds + ((kt+1)&1)*STEP;
      const char* lBn = lAn + ABYT;
      QR_A(0, lAn); QR_B(0, lBn);
      SCHB;
    }
    QMFMA(1,1);
  }
#undef QCHUNK
#undef QR_A
#undef QR_B
#undef QMFMA

  // ---- fused epilogue: bias + RoPE(+scale) + bf16 pack ----
  const int btype = (n0 >= H_*HD_) + (n0 >= H_*HD_ + KVH_*HD_);  // 0=Q 1=K 2=V
  const int colbase = n0 + wc*128 - (btype==1 ? H_*HD_ : btype==2 ? H_*HD_+KVH_*HD_ : 0);
  const int hloc = colbase >> 7;
  const float* bias = btype==0 ? bq : btype==1 ? bk : bv;
  u16* dst = btype==0 ? qb : btype==1 ? kb : vb;
  const int nheads = btype==0 ? H_ : KVH_;
  const float scale = btype==0 ? 0.08838834764831845f : 1.0f;

  float bb[8];
#pragma unroll
  for (int j = 0; j < 8; ++j) bb[j] = bias[colbase + j*16 + l15];

#pragma unroll
  for (int i = 0; i < 4; ++i)
#pragma unroll
    for (int r = 0; r < 4; ++r) {
      int sr = m0 + wr*64 + i*16 + l4*4 + r;
      int b_ = sr >> 10, s_ = sr & 1023;
      size_t obase = (((size_t)b_*nheads + hloc)*S_ + s_)*(size_t)HD_;
      if (btype < 2) {
#pragma unroll
        for (int j = 0; j < 4; ++j) {
          float cs = cosd[s_*64 + j*16 + l15];
          float sn = sind[s_*64 + j*16 + l15];
          float lo = acc[i][j][r]   + bb[j];
          float hi = acc[i][j+4][r] + bb[j+4];
          dst[obase + j*16 + l15]      = f2bf((lo*cs - hi*sn) * scale);
          dst[obase + 64 + j*16 + l15] = f2bf((hi*cs + lo*sn) * scale);
        }
      } else {
#pragma unroll
        for (int j = 0; j < 8; ++j)
          dst[obase + j*16 + l15] = f2bf(acc[i][j][r] + bb[j]);
      }
    }
}

// ==== Out-projection GEMM: BM=256 BN=128, reg-pipelined counted-lgkm schedule ====
// 512 thr = 8 waves, 2M x 4N (WM=128, WN=32). Grid (2048/256)x(4096/128) = 8x32 = 256.
__global__ __launch_bounds__(512, 2) void k_gemmo(
    const u16* __restrict__ A, const u16* __restrict__ Bt,
    float* __restrict__ C, int N, int K)
{
  constexpr int ABYT = 256*128, BBYT = 128*128, STEP = ABYT+BBYT;  // 48 KB
  __shared__ __align__(16) char lds[2*STEP];       // 96 KB

  const int cpx = (int)gridDim.x >> 3;
  const int wkid = ((int)blockIdx.x & 7)*cpx + ((int)blockIdx.x >> 3);
  const int NT = N / 128;
  const int m0 = (wkid / NT) * 256, n0 = (wkid % NT) * 128;
  const int tid = threadIdx.x, w = tid>>6, lane = tid&63;
  const int l15 = lane&15, l4 = lane>>4;
  const int wr = w>>2, wc = w&3;                   // 2M x 4N
  const int row0 = tid>>3;
  const int ss = (tid&7) ^ (row0&7);
  const int NK = K >> 6;

  f32x4 acc[8][2];
#pragma unroll
  for (int i = 0; i < 8; ++i)
#pragma unroll
    for (int j = 0; j < 2; ++j) acc[i][j] = (f32x4){0.f,0.f,0.f,0.f};

  bf16x8 af[2][4][2];    // [half][i][kk]
  bf16x8 bfr[2][2];      // [half][kk]

#define OCHUNK(kt_, part_, r0c_)                                              \
  __builtin_amdgcn_global_load_lds(                                           \
    (AS1 void*)(((part_) ? Bt + (size_t)(n0 + (r0c_) + row0)*K                \
                         : A  + (size_t)(m0 + (r0c_) + row0)*K)               \
                + (size_t)(kt_)*64 + ss*8),                                   \
    (AS3 void*)(lds + ((kt_)&1)*STEP + (part_)*ABYT + (r0c_)*128 + w*1024),   \
    16, 0, 0)

#define OR_A(mh_, lA_)                                                        \
  _Pragma("unroll") for (int i = 0; i < 4; ++i)                               \
  _Pragma("unroll") for (int kk = 0; kk < 2; ++kk) {                          \
    int row = wr*128 + ((mh_)*4 + i)*16 + l15;                                \
    af[mh_][i][kk] = *(const bf16x8*)((lA_) + row*128 + (((kk*4+l4) ^ (row&7)) << 4)); }

#define OR_B(nh_, lB_)                                                        \
  _Pragma("unroll") for (int kk = 0; kk < 2; ++kk) {                          \
    int row = wc*32 + (nh_)*16 + l15;                                         \
    bfr[nh_][kk] = *(const bf16x8*)((lB_) + row*128 + (((kk*4+l4) ^ (row&7)) << 4)); }

#define OMFMA(mh_, nh_)                                                       \
  __builtin_amdgcn_s_setprio(1);                                              \
  _Pragma("unroll") for (int i = 0; i < 4; ++i)                               \
  _Pragma("unroll") for (int kk = 0; kk < 2; ++kk)                            \
    acc[(mh_)*4+i][nh_] = __builtin_amdgcn_mfma_f32_16x16x32_bf16(            \
        af[mh_][i][kk], bfr[nh_][kk], acc[(mh_)*4+i][nh_], 0, 0, 0);          \
  __builtin_amdgcn_s_setprio(0);

  // prologue: tiles 0,1 (6 gloads each); wait tile0; read A0(8)+B0(2)
  OCHUNK(0,0,0); OCHUNK(0,0,64); OCHUNK(0,0,128); OCHUNK(0,0,192);
  OCHUNK(0,1,0); OCHUNK(0,1,64);
  OCHUNK(1,0,0); OCHUNK(1,0,64); OCHUNK(1,0,128); OCHUNK(1,0,192);
  OCHUNK(1,1,0); OCHUNK(1,1,64);
  asm volatile("s_waitcnt vmcnt(6)" ::: "memory");
  BAR; SCHB;
  {
    const char* lA0 = lds;
    const char* lB0 = lds + ABYT;
    OR_A(0, lA0); OR_B(0, lB0);
  }

  for (int kt = 0; kt < NK; ++kt) {
    const char* lA = lds + (kt&1)*STEP;
    const char* lB = lA + ABYT;
    // ph0: issue B1(2); drain A0,B0; MFMA(0,0)
    OR_B(1, lB);
    asm volatile("s_waitcnt lgkmcnt(2)" ::: "memory");
    SCHB;
    OMFMA(0,0);
    // ph1: issue A1(8); drain B1; barrier; stage B(kt+2); MFMA(0,1)
    OR_A(1, lA);
    asm volatile("s_waitcnt lgkmcnt(8)" ::: "memory");
    BAR; SCHB;
    if (kt+2 < NK) { OCHUNK(kt+2,1,0); OCHUNK(kt+2,1,64); }
    OMFMA(0,1);
    // ph2: drain A1; barrier; stage A(kt+2); MFMA(1,0)
    asm volatile("s_waitcnt lgkmcnt(0)" ::: "memory");
    BAR; SCHB;
    if (kt+2 < NK) { OCHUNK(kt+2,0,0); OCHUNK(kt+2,0,64); OCHUNK(kt+2,0,128); OCHUNK(kt+2,0,192); }
    OMFMA(1,0);
    // ph3: tile kt+1 resident; barrier; read its A0,B0; MFMA(1,1)
    if (kt+1 < NK) {
      if (kt+2 < NK) asm volatile("s_waitcnt vmcnt(6)" ::: "memory");
      else           asm volatile("s_waitcnt vmcnt(0)" ::: "memory");
      BAR; SCHB;
      const char* lAn = lds + ((kt+1)&1)*STEP;
      const char* lBn = lAn + ABYT;
      OR_A(0, lAn); OR_B(0, lBn);
      SCHB;
    }
    OMFMA(1,1);
  }
#undef OCHUNK
#undef OR_A
#undef OR_B
#undef OMFMA

#pragma unroll
  for (int i = 0; i < 8; ++i)
#pragma unroll
    for (int j = 0; j < 2; ++j) {
      int r0 = m0 + wr*128 + i*16 + l4*4;
      int c0 = n0 + wc*32 + j*16 + l15;
#pragma unroll
      for (int r = 0; r < 4; ++r)
        C[(size_t)(r0 + r) * N + c0] = acc[i][j][r];
    }
}

// ---------------- causal GQA flash attention: block-cooperative LDS-staged K/V -------
__global__ __launch_bounds__(256, 4) void k_attn(
    const u16* __restrict__ Q, const u16* __restrict__ Kc,
    const u16* __restrict__ Vt, u16* __restrict__ AO)
{
  __shared__ __align__(16) char Kls[2][16384];
  __shared__ __align__(16) char Vls[2][16384];
  __shared__ u16 Pl[4][1024];

  int id = blockIdx.x;
  int slot = id >> 3;
  int bg   = (id & 7)*2 + (slot & 1);
  int rem  = slot >> 1;
  int h_in = rem & 3, bx = rem >> 2;
  int b = bg >> 3, g = bg & 7, h = g*4 + h_in;
  int tA = bx, tB = 15 - bx;

  int tid = threadIdx.x, w = tid >> 6, lane = tid & 63;
  int l15 = lane & 15, l4 = lane >> 4;
  const u16* Qh = Q  + ((size_t)b*H_   + h) * S_ * HD_;
  const u16* Kp = Kc + ((size_t)b*KVH_ + g) * S_ * HD_;
  const u16* Vp = Vt + ((size_t)b*KVH_ + g) * (size_t)HD_ * S_;
  u16* AOh = AO + ((size_t)b*S_) * (H_*HD_) + h*HD_;
  char* Pw = (char*)&Pl[w][0];

  int kOff[4], vOff[4];
#pragma unroll
  for (int c = 0; c < 4; ++c) {
    int ci = c*256 + tid;
    int krow = ci >> 4, ks = ci & 15;
    kOff[c] = krow * HD_ + ((ks & 8) | ((ks & 7) ^ (krow & 7))) * 8;
    int vrow = ci >> 3, vs = ci & 7;
    vOff[c] = vrow * S_ + (vs ^ (vrow & 7)) * 8;
  }

#define ASTAGE(kv_, bb_) {                                                    \
    const u16* ks_ = Kp + (size_t)(kv_) * 64 * HD_;                           \
    const u16* vs_ = Vp + (size_t)(kv_) * 64;                                 \
    _Pragma("unroll") for (int c = 0; c < 4; ++c) {                           \
      __builtin_amdgcn_global_load_lds((AS1 void*)(ks_ + kOff[c]),            \
          (AS3 void*)(&Kls[bb_][0] + c*4096 + w*1024), 16, 0, 0);             \
      __builtin_amdgcn_global_load_lds((AS1 void*)(vs_ + vOff[c]),            \
          (AS3 void*)(&Vls[bb_][0] + c*4096 + w*1024), 16, 0, 0); } }

  bf16x8 qf[4];
#pragma unroll
  for (int kc = 0; kc < 4; ++kc)
    qf[kc] = *(const bf16x8*)(Qh + (size_t)(tA*64 + w*16 + l15)*HD_ + kc*32 + l4*8);

  f32x4 o[8];
#pragma unroll
  for (int n = 0; n < 8; ++n) o[n] = (f32x4){0.f,0.f,0.f,0.f};
  float mrow[4] = {-3e38f,-3e38f,-3e38f,-3e38f};
  float lrow[4] = {0.f,0.f,0.f,0.f};

  ASTAGE(0, 0);
  asm volatile("s_waitcnt vmcnt(0)" ::: "memory");
  __builtin_amdgcn_s_barrier();

  const int NIT = tA + tB + 2;
  int buf = 0;
  for (int it = 0; it < NIT; ++it) {
    bool phA = (it <= tA);
    int kv = phA ? it : it - tA - 1;
    int qt = phA ? tA : tB;
    if (it + 1 < NIT) {
      int kvn = (it + 1 <= tA) ? it + 1 : it - tA;
      ASTAGE(kvn, buf ^ 1);
    }
    const char* Ksb = &Kls[buf][0];
    const char* Vsb = &Vls[buf][0];

    f32x4 sc[4];
    __builtin_amdgcn_s_setprio(1);
#pragma unroll
    for (int ct = 0; ct < 4; ++ct) {
      f32x4 s4 = (f32x4){0.f,0.f,0.f,0.f};
#pragma unroll
      for (int kc = 0; kc < 4; ++kc) {
        int row = ct*16 + l15, s = kc*4 + l4;
        bf16x8 kf = *(const bf16x8*)(Ksb + row*256 + ((((s & 7) ^ (row & 7)) | (s & 8)) << 4));
        s4 = __builtin_amdgcn_mfma_f32_16x16x32_bf16(qf[kc], kf, s4, 0, 0, 0);
      }
      sc[ct] = s4;
    }
    __builtin_amdgcn_s_setprio(0);

    if (kv == qt) {
      int qrow0 = qt*64 + w*16;
#pragma unroll
      for (int ct = 0; ct < 4; ++ct)
#pragma unroll
        for (int r = 0; r < 4; ++r) {
          int col = kv*64 + ct*16 + l15;
          if (col > qrow0 + l4*4 + r) sc[ct][r] = -1e9f;
        }
    }

    float f[4];
#pragma unroll
    for (int r = 0; r < 4; ++r) {
      float mx = fmaxf(fmaxf(sc[0][r], sc[1][r]), fmaxf(sc[2][r], sc[3][r]));
      mx = fmaxf(mx, __shfl_xor(mx, 1));
      mx = fmaxf(mx, __shfl_xor(mx, 2));
      mx = fmaxf(mx, __shfl_xor(mx, 4));
      mx = fmaxf(mx, __shfl_xor(mx, 8));
      float nm = fmaxf(mrow[r], mx);
      f[r] = __expf(mrow[r] - nm);
      mrow[r] = nm;
    }
    float rs[4] = {0.f,0.f,0.f,0.f};
#pragma unroll
    for (int ct = 0; ct < 4; ++ct)
#pragma unroll
      for (int r = 0; r < 4; ++r) {
        float p = __expf(sc[ct][r] - mrow[r]);
        rs[r] += p;
        int row = l4*4 + r, col = ct*16 + l15;
        int byte = row*128 + (((col >> 3) ^ (row & 7)) << 4) + (col & 7)*2;
        *(u16*)(Pw + byte) = f2bf(p);
      }
#pragma unroll
    for (int r = 0; r < 4; ++r) {
      float sum = rs[r];
      sum += __shfl_xor(sum, 1);
      sum += __shfl_xor(sum, 2);
      sum += __shfl_xor(sum, 4);
      sum += __shfl_xor(sum, 8);
      lrow[r] = lrow[r]*f[r] + sum;
    }
#pragma unroll
    for (int n = 0; n < 8; ++n)
#pragma unroll
      for (int r = 0; r < 4; ++r) o[n][r] *= f[r];

    __builtin_amdgcn_s_setprio(1);
#pragma unroll
    for (int kk = 0; kk < 2; ++kk) {
      int pbyte = l15*128 + (((kk*4 + l4) ^ (l15 & 7)) << 4);
      bf16x8 pf = *(const bf16x8*)(Pw + pbyte);
#pragma unroll
      for (int n = 0; n < 8; ++n) {
        int vrow = n*16 + l15, s = kk*4 + l4;
        bf16x8 vf = *(const bf16x8*)(Vsb + vrow*128 + ((s ^ (vrow & 7)) << 4));
        o[n] = __builtin_amdgcn_mfma_f32_16x16x32_bf16(pf, vf, o[n], 0, 0, 0);
      }
    }
    __builtin_amdgcn_s_setprio(0);

    if (it == tA) {
#pragma unroll
      for (int n = 0; n < 8; ++n)
#pragma unroll
        for (int r = 0; r < 4; ++r) {
          int srow = tA*64 + w*16 + l4*4 + r;
          AOh[(size_t)srow * (H_*HD_) + n*16 + l15] = f2bf(o[n][r] / lrow[r]);
        }
#pragma unroll
      for (int n = 0; n < 8; ++n) o[n] = (f32x4){0.f,0.f,0.f,0.f};
#pragma unroll
      for (int r = 0; r < 4; ++r) { mrow[r] = -3e38f; lrow[r] = 0.f; }
#pragma unroll
      for (int kc = 0; kc < 4; ++kc)
        qf[kc] = *(const bf16x8*)(Qh + (size_t)(tB*64 + w*16 + l15)*HD_ + kc*32 + l4*8);
    }

    asm volatile("s_waitcnt vmcnt(0)" ::: "memory");
    __builtin_amdgcn_s_barrier();
    buf ^= 1;
  }
#undef ASTAGE

#pragma unroll
  for (int n = 0; n < 8; ++n)
#pragma unroll
    for (int r = 0; r < 4; ++r) {
      int srow = tB*64 + w*16 + l4*4 + r;
      AOh[(size_t)srow * (H_*HD_) + n*16 + l15] = f2bf(o[n][r] / lrow[r]);
    }
}

extern "C" void kernel_launch(void* const* d_in, const int* in_sizes, int n_in,
                              void* d_out, int out_size, void* d_ws, size_t ws_size,
                              hipStream_t stream) {
  (void)in_sizes; (void)n_in; (void)out_size; (void)ws_size;
  const float* x   = (const float*)d_in[0];
  const int*   sid = (const int*)  d_in[1];
  // d_in[2] = cache (dead), d_in[3] = mask (dead: causal re-derived)
  const float* Wq  = (const float*)d_in[4];
  const float* bq  = (const float*)d_in[5];
  const float* Wk  = (const float*)d_in[6];
  const float* bk  = (const float*)d_in[7];
  const float* Wv  = (const float*)d_in[8];
  const float* bv  = (const float*)d_in[9];
  const float* Wo  = (const float*)d_in[10];
  float* out = (float*)d_out;

  char* ws = (char*)d_ws;
  u16*   xb   = (u16*)  (ws);                    // 16 MB (aliased by AO later)
  u16*   WB   = (u16*)  (ws + 16777216);         // 48 MB  [6144][4096]
  u16*   WoT  = (u16*)  (ws + 67108864);         // 32 MB  [4096][4096]
  u16*   qb   = (u16*)  (ws + 150994944);        // 16 MB  [B][H][S][HD]
  u16*   kb   = (u16*)  (ws + 167772160);        //  4 MB  [B][KVH][S][HD]
  u16*   vb   = (u16*)  (ws + 171966464);        //  4 MB
  u16*   VT   = (u16*)  (ws + 176160768);        //  4 MB  [B][KVH][HD][S]
  float* cosd = (float*)(ws + 180355072);        // 256 KB
  float* sind = (float*)(ws + 180617216);        // 256 KB
  u16*   AO   = xb;                              // attention output reuses xb

  dim3 tb(32, 8);
  k_convert<<<8192, 256, 0, stream>>>(x, xb, (2048*4096)/4);
  k_transpose_w<<<dim3(128,128), tb, 0, stream>>>(Wq, WB, 4096, 4096);
  k_transpose_w<<<dim3( 32,128), tb, 0, stream>>>(Wk, WB + (size_t)4096*4096, 4096, 1024);
  k_transpose_w<<<dim3( 32,128), tb, 0, stream>>>(Wv, WB + (size_t)5120*4096, 4096, 1024);
  k_transpose_w<<<dim3(128,128), tb, 0, stream>>>(Wo, WoT, 4096, 4096);
  k_rope<<<256, 256, 0, stream>>>(sid, cosd, sind);
  k_gemmq<<<192, 512, 0, stream>>>(xb, WB, bq, bk, bv, cosd, sind, qb, kb, vb);
  k_transpose_v<<<dim3(32,4,16), tb, 0, stream>>>(vb, VT);
  k_attn<<<512, 256, 0, stream>>>(qb, kb, VT, AO);
  k_gemmo<<<256, 512, 0, stream>>>(AO, WoT, out, 4096, 4096);
}

// Round 13
// 286.403 us; speedup vs baseline: 1.8049x; 1.0267x over previous
//
#include <hip/hip_runtime.h>
#include <hip/hip_bf16.h>

typedef unsigned short u16;
typedef unsigned int   u32;
using bf16x8 = __attribute__((ext_vector_type(8))) short;
using f32x4  = __attribute__((ext_vector_type(4))) float;

#define AS1 __attribute__((address_space(1)))
#define AS3 __attribute__((address_space(3)))

static constexpr int S_   = 1024;
static constexpr int D_   = 4096;
static constexpr int H_   = 32;
static constexpr int KVH_ = 8;
static constexpr int HD_  = 128;
static constexpr int NQKV = H_*HD_ + 2*KVH_*HD_;   // 6144

__device__ __forceinline__ u16 f2bf(float f) {
  union { float f; u32 u; } v; v.f = f;
  u32 r = v.u + 0x7FFFu + ((v.u >> 16) & 1u);      // RTNE
  return (u16)(r >> 16);
}

// ---------------- x f32 -> bf16 ----------------
__global__ void k_convert(const float* __restrict__ src, u16* __restrict__ dst, int n4) {
  int i = blockIdx.x * blockDim.x + threadIdx.x;
  if (i >= n4) return;
  float4 v = ((const float4*)src)[i];
  ushort4 o;
  o.x = f2bf(v.x); o.y = f2bf(v.y); o.z = f2bf(v.z); o.w = f2bf(v.w);
  ((ushort4*)dst)[i] = o;
}

// -------- W [K][N] f32 -> Wt [N][K] bf16, 64x64 tiles, vectorized --------
__global__ __launch_bounds__(256) void k_transpose_w(
    const float* __restrict__ src, u16* __restrict__ dst, int K, int N) {
  __shared__ float t[64][65];
  int k0 = blockIdx.y * 64, n0 = blockIdx.x * 64;
  int tid = threadIdx.x;
  int lr = tid >> 4;              // k-row 0..15 (x4 iters)
  int lc = (tid & 15) * 4;        // n-col
#pragma unroll
  for (int i = 0; i < 4; ++i) {
    float4 v = *(const float4*)&src[(size_t)(k0 + lr + i*16) * N + n0 + lc];
    t[lc+0][lr + i*16] = v.x;
    t[lc+1][lr + i*16] = v.y;
    t[lc+2][lr + i*16] = v.z;
    t[lc+3][lr + i*16] = v.w;
  }
  __syncthreads();
  int wn = tid >> 3;              // n-row 0..31 (x2 iters)
  int wk = (tid & 7) * 8;         // 8 k values
#pragma unroll
  for (int i = 0; i < 2; ++i) {
    const float* row = &t[wn + i*32][wk];
    ushort4 a, b;
    a.x = f2bf(row[0]); a.y = f2bf(row[1]); a.z = f2bf(row[2]); a.w = f2bf(row[3]);
    b.x = f2bf(row[4]); b.y = f2bf(row[5]); b.z = f2bf(row[6]); b.w = f2bf(row[7]);
    u16* o = &dst[(size_t)(n0 + wn + i*32) * K + k0 + wk];
    *(ushort4*)o = a;
    *(ushort4*)(o + 4) = b;
  }
}

// ---------------- V [BG][S][HD] bf16 -> Vt [BG][HD][S] bf16 ----------------
__global__ void k_transpose_v(const u16* __restrict__ src, u16* __restrict__ dst) {
  __shared__ u16 t[32][33];
  int bg = blockIdx.z;
  int s0 = blockIdx.x * 32, h0 = blockIdx.y * 32;
  src += (size_t)bg * S_ * HD_;
  dst += (size_t)bg * S_ * HD_;
  int tx = threadIdx.x, ty = threadIdx.y;
#pragma unroll
  for (int i = 0; i < 4; ++i)
    t[ty + i*8][tx] = src[(size_t)(s0 + ty + i*8) * HD_ + h0 + tx];
  __syncthreads();
#pragma unroll
  for (int i = 0; i < 4; ++i)
    dst[(size_t)(h0 + ty + i*8) * S_ + s0 + tx] = t[tx][ty + i*8];
}

// ---------------- RoPE tables: cos/sin [S][64] f32 ----------------
__global__ void k_rope(const int* __restrict__ sidx, float* __restrict__ cosd,
                       float* __restrict__ sind) {
  int i = blockIdx.x * blockDim.x + threadIdx.x;    // S*64
  int s = i >> 6, d = i & 63;
  float pos  = (float)sidx[s];
  float invf = expf(-0.21586735246819178f * (float)d);  // 1e6^(-d/64)
  float ph   = pos * invf;
  cosd[i] = cosf(ph);
  sind[i] = sinf(ph);
}

#define BAR   __builtin_amdgcn_s_barrier()
#define SCHB  __builtin_amdgcn_sched_barrier(0)

// ==== QKV GEMM (M=2048, N=6144, K=4096), reg-pipelined counted-lgkm schedule ====
__global__ __launch_bounds__(512, 2) void k_gemmq(
    const u16* __restrict__ A, const u16* __restrict__ Bt,
    const float* __restrict__ bq, const float* __restrict__ bk,
    const float* __restrict__ bv,
    const float* __restrict__ cosd, const float* __restrict__ sind,
    u16* __restrict__ qb, u16* __restrict__ kb, u16* __restrict__ vb)
{
  constexpr int K = 4096;
  constexpr int ABYT = 256*128, BBYT = 256*128, STEP = ABYT+BBYT;
  __shared__ __align__(16) char lds[2*STEP];       // 128 KB

  const int cpx = (int)gridDim.x >> 3;             // 24
  const int wkid = ((int)blockIdx.x & 7)*cpx + ((int)blockIdx.x >> 3);
  const int NT = 24;
  const int m0 = (wkid / NT) * 256, n0 = (wkid % NT) * 256;
  const int tid = threadIdx.x, w = tid>>6, lane = tid&63;
  const int l15 = lane&15, l4 = lane>>4;
  const int wr = w>>1, wc = w&1;                   // 4M x 2N
  const int row0 = tid>>3;
  const int ss = (tid&7) ^ (row0&7);
  const int NK = K >> 6;                           // 64

  f32x4 acc[4][8];
#pragma unroll
  for (int i = 0; i < 4; ++i)
#pragma unroll
    for (int j = 0; j < 8; ++j) acc[i][j] = (f32x4){0.f,0.f,0.f,0.f};

  bf16x8 af[2][2][2];    // [half][i2][kk]
  bf16x8 bfr[2][4][2];   // [half][jj][kk]

#define QCHUNK(kt_, part_, r0c_)                                              \
  __builtin_amdgcn_global_load_lds(                                           \
    (AS1 void*)(((part_) ? Bt + (size_t)(n0 + (r0c_) + row0)*K                \
                         : A  + (size_t)(m0 + (r0c_) + row0)*K)               \
                + (size_t)(kt_)*64 + ss*8),                                   \
    (AS3 void*)(lds + ((kt_)&1)*STEP + (part_)*ABYT + (r0c_)*128 + w*1024),   \
    16, 0, 0)

#define QR_A(mh_, lA_)                                                        \
  _Pragma("unroll") for (int i2 = 0; i2 < 2; ++i2)                            \
  _Pragma("unroll") for (int kk = 0; kk < 2; ++kk) {                          \
    int row = wr*64 + ((mh_)*2 + i2)*16 + l15;                                \
    af[mh_][i2][kk] = *(const bf16x8*)((lA_) + row*128 + (((kk*4+l4) ^ (row&7)) << 4)); }

#define QR_B(nh_, lB_)                                                        \
  _Pragma("unroll") for (int jj = 0; jj < 4; ++jj)                            \
  _Pragma("unroll") for (int kk = 0; kk < 2; ++kk) {                          \
    int row = wc*128 + ((nh_)*4 + jj)*16 + l15;                               \
    bfr[nh_][jj][kk] = *(const bf16x8*)((lB_) + row*128 + (((kk*4+l4) ^ (row&7)) << 4)); }

#define QMFMA(mh_, nh_)                                                       \
  __builtin_amdgcn_s_setprio(1);                                              \
  _Pragma("unroll") for (int i2 = 0; i2 < 2; ++i2)                            \
  _Pragma("unroll") for (int jj = 0; jj < 4; ++jj)                            \
  _Pragma("unroll") for (int kk = 0; kk < 2; ++kk)                            \
    acc[(mh_)*2+i2][(nh_)*4+jj] = __builtin_amdgcn_mfma_f32_16x16x32_bf16(    \
        af[mh_][i2][kk], bfr[nh_][jj][kk], acc[(mh_)*2+i2][(nh_)*4+jj], 0, 0, 0); \
  __builtin_amdgcn_s_setprio(0);

  // prologue: stage tiles 0,1; wait tile0; read its A0,B0
  QCHUNK(0,0,0); QCHUNK(0,0,64); QCHUNK(0,0,128); QCHUNK(0,0,192);
  QCHUNK(0,1,0); QCHUNK(0,1,64); QCHUNK(0,1,128); QCHUNK(0,1,192);
  QCHUNK(1,0,0); QCHUNK(1,0,64); QCHUNK(1,0,128); QCHUNK(1,0,192);
  QCHUNK(1,1,0); QCHUNK(1,1,64); QCHUNK(1,1,128); QCHUNK(1,1,192);
  asm volatile("s_waitcnt vmcnt(8)" ::: "memory");
  BAR; SCHB;
  {
    const char* lA0 = lds;
    const char* lB0 = lds + ABYT;
    QR_A(0, lA0); QR_B(0, lB0);
  }

  for (int kt = 0; kt < NK; ++kt) {
    const char* lA = lds + (kt&1)*STEP;
    const char* lB = lA + ABYT;
    QR_B(1, lB);
    asm volatile("s_waitcnt lgkmcnt(8)" ::: "memory");
    SCHB;
    QMFMA(0,0);
    QR_A(1, lA);
    asm volatile("s_waitcnt lgkmcnt(4)" ::: "memory");
    BAR; SCHB;
    if (kt+2 < NK) { QCHUNK(kt+2,1,0); QCHUNK(kt+2,1,64); QCHUNK(kt+2,1,128); QCHUNK(kt+2,1,192); }
    QMFMA(0,1);
    asm volatile("s_waitcnt lgkmcnt(0)" ::: "memory");
    BAR; SCHB;
    if (kt+2 < NK) { QCHUNK(kt+2,0,0); QCHUNK(kt+2,0,64); QCHUNK(kt+2,0,128); QCHUNK(kt+2,0,192); }
    QMFMA(1,0);
    if (kt+1 < NK) {
      if (kt+2 < NK) asm volatile("s_waitcnt vmcnt(8)" ::: "memory");
      else           asm volatile("s_waitcnt vmcnt(0)" ::: "memory");
      BAR; SCHB;
      const char* lAn = lds + ((kt+1)&1)*STEP;
      const char* lBn = lAn + ABYT;
      QR_A(0, lAn); QR_B(0, lBn);
      SCHB;
    }
    QMFMA(1,1);
  }
#undef QCHUNK
#undef QR_A
#undef QR_B
#undef QMFMA

  // ---- fused epilogue: bias + RoPE(+scale) + bf16 pack ----
  const int btype = (n0 >= H_*HD_) + (n0 >= H_*HD_ + KVH_*HD_);  // 0=Q 1=K 2=V
  const int colbase = n0 + wc*128 - (btype==1 ? H_*HD_ : btype==2 ? H_*HD_+KVH_*HD_ : 0);
  const int hloc = colbase >> 7;
  const float* bias = btype==0 ? bq : btype==1 ? bk : bv;
  u16* dst = btype==0 ? qb : btype==1 ? kb : vb;
  const int nheads = btype==0 ? H_ : KVH_;
  const float scale = btype==0 ? 0.08838834764831845f : 1.0f;

  float bb[8];
#pragma unroll
  for (int j = 0; j < 8; ++j) bb[j] = bias[colbase + j*16 + l15];

#pragma unroll
  for (int i = 0; i < 4; ++i)
#pragma unroll
    for (int r = 0; r < 4; ++r) {
      int sr = m0 + wr*64 + i*16 + l4*4 + r;
      int b_ = sr >> 10, s_ = sr & 1023;
      size_t obase = (((size_t)b_*nheads + hloc)*S_ + s_)*(size_t)HD_;
      if (btype < 2) {
#pragma unroll
        for (int j = 0; j < 4; ++j) {
          float cs = cosd[s_*64 + j*16 + l15];
          float sn = sind[s_*64 + j*16 + l15];
          float lo = acc[i][j][r]   + bb[j];
          float hi = acc[i][j+4][r] + bb[j+4];
          dst[obase + j*16 + l15]      = f2bf((lo*cs - hi*sn) * scale);
          dst[obase + 64 + j*16 + l15] = f2bf((hi*cs + lo*sn) * scale);
        }
      } else {
#pragma unroll
        for (int j = 0; j < 8; ++j)
          dst[obase + j*16 + l15] = f2bf(acc[i][j][r] + bb[j]);
      }
    }
}

// ==== Out-projection GEMM: BM=128 BN=256, reg-pipelined counted-lgkm schedule ====
// 512 thr = 8 waves, 2M x 4N (wave = 64 x 64, acc[4][4]): MFMA:ds_read = 32:16.
// Grid (2048/128)x(4096/256) = 16x16 = 256 blocks -> full CU coverage. LDS 96 KB.
__global__ __launch_bounds__(512, 2) void k_gemmo(
    const u16* __restrict__ A, const u16* __restrict__ Bt,
    float* __restrict__ C, int N, int K)
{
  constexpr int ABYT = 128*128, BBYT = 256*128, STEP = ABYT+BBYT;  // 48 KB
  __shared__ __align__(16) char lds[2*STEP];       // 96 KB

  const int cpx = (int)gridDim.x >> 3;
  const int wkid = ((int)blockIdx.x & 7)*cpx + ((int)blockIdx.x >> 3);
  const int NT = N / 256;                          // 16
  const int m0 = (wkid / NT) * 128, n0 = (wkid % NT) * 256;
  const int tid = threadIdx.x, w = tid>>6, lane = tid&63;
  const int l15 = lane&15, l4 = lane>>4;
  const int wr = w>>2, wc = w&3;                   // 2M x 4N, wave 64x64
  const int row0 = tid>>3;
  const int ss = (tid&7) ^ (row0&7);
  const int NK = K >> 6;

  f32x4 acc[4][4];
#pragma unroll
  for (int i = 0; i < 4; ++i)
#pragma unroll
    for (int j = 0; j < 4; ++j) acc[i][j] = (f32x4){0.f,0.f,0.f,0.f};

  bf16x8 af[2][2][2];    // [half][i2][kk]  (half = 2 row-frags)
  bf16x8 bfr[2][2][2];   // [half][j2][kk]

#define OCHUNK(kt_, part_, r0c_)                                              \
  __builtin_amdgcn_global_load_lds(                                           \
    (AS1 void*)(((part_) ? Bt + (size_t)(n0 + (r0c_) + row0)*K                \
                         : A  + (size_t)(m0 + (r0c_) + row0)*K)               \
                + (size_t)(kt_)*64 + ss*8),                                   \
    (AS3 void*)(lds + ((kt_)&1)*STEP + (part_)*ABYT + (r0c_)*128 + w*1024),   \
    16, 0, 0)

#define OR_A(mh_, lA_)                                                        \
  _Pragma("unroll") for (int i2 = 0; i2 < 2; ++i2)                            \
  _Pragma("unroll") for (int kk = 0; kk < 2; ++kk) {                          \
    int row = wr*64 + ((mh_)*2 + i2)*16 + l15;                                \
    af[mh_][i2][kk] = *(const bf16x8*)((lA_) + row*128 + (((kk*4+l4) ^ (row&7)) << 4)); }

#define OR_B(nh_, lB_)                                                        \
  _Pragma("unroll") for (int j2 = 0; j2 < 2; ++j2)                            \
  _Pragma("unroll") for (int kk = 0; kk < 2; ++kk) {                          \
    int row = wc*64 + ((nh_)*2 + j2)*16 + l15;                                \
    bfr[nh_][j2][kk] = *(const bf16x8*)((lB_) + row*128 + (((kk*4+l4) ^ (row&7)) << 4)); }

#define OMFMA(mh_, nh_)                                                       \
  __builtin_amdgcn_s_setprio(1);                                              \
  _Pragma("unroll") for (int i2 = 0; i2 < 2; ++i2)                            \
  _Pragma("unroll") for (int j2 = 0; j2 < 2; ++j2)                            \
  _Pragma("unroll") for (int kk = 0; kk < 2; ++kk)                            \
    acc[(mh_)*2+i2][(nh_)*2+j2] = __builtin_amdgcn_mfma_f32_16x16x32_bf16(    \
        af[mh_][i2][kk], bfr[nh_][j2][kk], acc[(mh_)*2+i2][(nh_)*2+j2], 0, 0, 0); \
  __builtin_amdgcn_s_setprio(0);

  // prologue: tiles 0,1 (A 2 + B 4 chunks each); wait tile0; read A0(4)+B0(4)
  OCHUNK(0,0,0); OCHUNK(0,0,64);
  OCHUNK(0,1,0); OCHUNK(0,1,64); OCHUNK(0,1,128); OCHUNK(0,1,192);
  OCHUNK(1,0,0); OCHUNK(1,0,64);
  OCHUNK(1,1,0); OCHUNK(1,1,64); OCHUNK(1,1,128); OCHUNK(1,1,192);
  asm volatile("s_waitcnt vmcnt(6)" ::: "memory");
  BAR; SCHB;
  {
    const char* lA0 = lds;
    const char* lB0 = lds + ABYT;
    OR_A(0, lA0); OR_B(0, lB0);
  }

  for (int kt = 0; kt < NK; ++kt) {
    const char* lA = lds + (kt&1)*STEP;
    const char* lB = lA + ABYT;
    // ph0: issue B1(4); drain A0,B0 (leave 4); MFMA(0,0)
    OR_B(1, lB);
    asm volatile("s_waitcnt lgkmcnt(4)" ::: "memory");
    SCHB;
    OMFMA(0,0);
    // ph1: issue A1(4); drain B1 (leave 4); barrier; stage B(kt+2); MFMA(0,1)
    OR_A(1, lA);
    asm volatile("s_waitcnt lgkmcnt(4)" ::: "memory");
    BAR; SCHB;
    if (kt+2 < NK) { OCHUNK(kt+2,1,0); OCHUNK(kt+2,1,64); OCHUNK(kt+2,1,128); OCHUNK(kt+2,1,192); }
    OMFMA(0,1);
    // ph2: drain A1; barrier; stage A(kt+2); MFMA(1,0)
    asm volatile("s_waitcnt lgkmcnt(0)" ::: "memory");
    BAR; SCHB;
    if (kt+2 < NK) { OCHUNK(kt+2,0,0); OCHUNK(kt+2,0,64); }
    OMFMA(1,0);
    // ph3: tile kt+1 resident; barrier; read its A0,B0; MFMA(1,1)
    if (kt+1 < NK) {
      if (kt+2 < NK) asm volatile("s_waitcnt vmcnt(6)" ::: "memory");
      else           asm volatile("s_waitcnt vmcnt(0)" ::: "memory");
      BAR; SCHB;
      const char* lAn = lds + ((kt+1)&1)*STEP;
      const char* lBn = lAn + ABYT;
      OR_A(0, lAn); OR_B(0, lBn);
      SCHB;
    }
    OMFMA(1,1);
  }
#undef OCHUNK
#undef OR_A
#undef OR_B
#undef OMFMA

#pragma unroll
  for (int i = 0; i < 4; ++i)
#pragma unroll
    for (int j = 0; j < 4; ++j) {
      int r0 = m0 + wr*64 + i*16 + l4*4;
      int c0 = n0 + wc*64 + j*16 + l15;
#pragma unroll
      for (int r = 0; r < 4; ++r)
        C[(size_t)(r0 + r) * N + c0] = acc[i][j][r];
    }
}

// ---------------- causal GQA flash attention: block-cooperative LDS-staged K/V -------
__global__ __launch_bounds__(256, 4) void k_attn(
    const u16* __restrict__ Q, const u16* __restrict__ Kc,
    const u16* __restrict__ Vt, u16* __restrict__ AO)
{
  __shared__ __align__(16) char Kls[2][16384];
  __shared__ __align__(16) char Vls[2][16384];
  __shared__ u16 Pl[4][1024];

  int id = blockIdx.x;
  int slot = id >> 3;
  int bg   = (id & 7)*2 + (slot & 1);
  int rem  = slot >> 1;
  int h_in = rem & 3, bx = rem >> 2;
  int b = bg >> 3, g = bg & 7, h = g*4 + h_in;
  int tA = bx, tB = 15 - bx;

  int tid = threadIdx.x, w = tid >> 6, lane = tid & 63;
  int l15 = lane & 15, l4 = lane >> 4;
  const u16* Qh = Q  + ((size_t)b*H_   + h) * S_ * HD_;
  const u16* Kp = Kc + ((size_t)b*KVH_ + g) * S_ * HD_;
  const u16* Vp = Vt + ((size_t)b*KVH_ + g) * (size_t)HD_ * S_;
  u16* AOh = AO + ((size_t)b*S_) * (H_*HD_) + h*HD_;
  char* Pw = (char*)&Pl[w][0];

  int kOff[4], vOff[4];
#pragma unroll
  for (int c = 0; c < 4; ++c) {
    int ci = c*256 + tid;
    int krow = ci >> 4, ks = ci & 15;
    kOff[c] = krow * HD_ + ((ks & 8) | ((ks & 7) ^ (krow & 7))) * 8;
    int vrow = ci >> 3, vs = ci & 7;
    vOff[c] = vrow * S_ + (vs ^ (vrow & 7)) * 8;
  }

#define ASTAGE(kv_, bb_) {                                                    \
    const u16* ks_ = Kp + (size_t)(kv_) * 64 * HD_;                           \
    const u16* vs_ = Vp + (size_t)(kv_) * 64;                                 \
    _Pragma("unroll") for (int c = 0; c < 4; ++c) {                           \
      __builtin_amdgcn_global_load_lds((AS1 void*)(ks_ + kOff[c]),            \
          (AS3 void*)(&Kls[bb_][0] + c*4096 + w*1024), 16, 0, 0);             \
      __builtin_amdgcn_global_load_lds((AS1 void*)(vs_ + vOff[c]),            \
          (AS3 void*)(&Vls[bb_][0] + c*4096 + w*1024), 16, 0, 0); } }

  bf16x8 qf[4];
#pragma unroll
  for (int kc = 0; kc < 4; ++kc)
    qf[kc] = *(const bf16x8*)(Qh + (size_t)(tA*64 + w*16 + l15)*HD_ + kc*32 + l4*8);

  f32x4 o[8];
#pragma unroll
  for (int n = 0; n < 8; ++n) o[n] = (f32x4){0.f,0.f,0.f,0.f};
  float mrow[4] = {-3e38f,-3e38f,-3e38f,-3e38f};
  float lrow[4] = {0.f,0.f,0.f,0.f};

  ASTAGE(0, 0);
  asm volatile("s_waitcnt vmcnt(0)" ::: "memory");
  __builtin_amdgcn_s_barrier();

  const int NIT = tA + tB + 2;
  int buf = 0;
  for (int it = 0; it < NIT; ++it) {
    bool phA = (it <= tA);
    int kv = phA ? it : it - tA - 1;
    int qt = phA ? tA : tB;
    if (it + 1 < NIT) {
      int kvn = (it + 1 <= tA) ? it + 1 : it - tA;
      ASTAGE(kvn, buf ^ 1);
    }
    const char* Ksb = &Kls[buf][0];
    const char* Vsb = &Vls[buf][0];

    f32x4 sc[4];
    __builtin_amdgcn_s_setprio(1);
#pragma unroll
    for (int ct = 0; ct < 4; ++ct) {
      f32x4 s4 = (f32x4){0.f,0.f,0.f,0.f};
#pragma unroll
      for (int kc = 0; kc < 4; ++kc) {
        int row = ct*16 + l15, s = kc*4 + l4;
        bf16x8 kf = *(const bf16x8*)(Ksb + row*256 + ((((s & 7) ^ (row & 7)) | (s & 8)) << 4));
        s4 = __builtin_amdgcn_mfma_f32_16x16x32_bf16(qf[kc], kf, s4, 0, 0, 0);
      }
      sc[ct] = s4;
    }
    __builtin_amdgcn_s_setprio(0);

    if (kv == qt) {
      int qrow0 = qt*64 + w*16;
#pragma unroll
      for (int ct = 0; ct < 4; ++ct)
#pragma unroll
        for (int r = 0; r < 4; ++r) {
          int col = kv*64 + ct*16 + l15;
          if (col > qrow0 + l4*4 + r) sc[ct][r] = -1e9f;
        }
    }

    float f[4];
#pragma unroll
    for (int r = 0; r < 4; ++r) {
      float mx = fmaxf(fmaxf(sc[0][r], sc[1][r]), fmaxf(sc[2][r], sc[3][r]));
      mx = fmaxf(mx, __shfl_xor(mx, 1));
      mx = fmaxf(mx, __shfl_xor(mx, 2));
      mx = fmaxf(mx, __shfl_xor(mx, 4));
      mx = fmaxf(mx, __shfl_xor(mx, 8));
      float nm = fmaxf(mrow[r], mx);
      f[r] = __expf(mrow[r] - nm);
      mrow[r] = nm;
    }
    float rs[4] = {0.f,0.f,0.f,0.f};
#pragma unroll
    for (int ct = 0; ct < 4; ++ct)
#pragma unroll
      for (int r = 0; r < 4; ++r) {
        float p = __expf(sc[ct][r] - mrow[r]);
        rs[r] += p;
        int row = l4*4 + r, col = ct*16 + l15;
        int byte = row*128 + (((col >> 3) ^ (row & 7)) << 4) + (col & 7)*2;
        *(u16*)(Pw + byte) = f2bf(p);
      }
#pragma unroll
    for (int r = 0; r < 4; ++r) {
      float sum = rs[r];
      sum += __shfl_xor(sum, 1);
      sum += __shfl_xor(sum, 2);
      sum += __shfl_xor(sum, 4);
      sum += __shfl_xor(sum, 8);
      lrow[r] = lrow[r]*f[r] + sum;
    }
#pragma unroll
    for (int n = 0; n < 8; ++n)
#pragma unroll
      for (int r = 0; r < 4; ++r) o[n][r] *= f[r];

    __builtin_amdgcn_s_setprio(1);
#pragma unroll
    for (int kk = 0; kk < 2; ++kk) {
      int pbyte = l15*128 + (((kk*4 + l4) ^ (l15 & 7)) << 4);
      bf16x8 pf = *(const bf16x8*)(Pw + pbyte);
#pragma unroll
      for (int n = 0; n < 8; ++n) {
        int vrow = n*16 + l15, s = kk*4 + l4;
        bf16x8 vf = *(const bf16x8*)(Vsb + vrow*128 + ((s ^ (vrow & 7)) << 4));
        o[n] = __builtin_amdgcn_mfma_f32_16x16x32_bf16(pf, vf, o[n], 0, 0, 0);
      }
    }
    __builtin_amdgcn_s_setprio(0);

    if (it == tA) {
#pragma unroll
      for (int n = 0; n < 8; ++n)
#pragma unroll
        for (int r = 0; r < 4; ++r) {
          int srow = tA*64 + w*16 + l4*4 + r;
          AOh[(size_t)srow * (H_*HD_) + n*16 + l15] = f2bf(o[n][r] / lrow[r]);
        }
#pragma unroll
      for (int n = 0; n < 8; ++n) o[n] = (f32x4){0.f,0.f,0.f,0.f};
#pragma unroll
      for (int r = 0; r < 4; ++r) { mrow[r] = -3e38f; lrow[r] = 0.f; }
#pragma unroll
      for (int kc = 0; kc < 4; ++kc)
        qf[kc] = *(const bf16x8*)(Qh + (size_t)(tB*64 + w*16 + l15)*HD_ + kc*32 + l4*8);
    }

    asm volatile("s_waitcnt vmcnt(0)" ::: "memory");
    __builtin_amdgcn_s_barrier();
    buf ^= 1;
  }
#undef ASTAGE

#pragma unroll
  for (int n = 0; n < 8; ++n)
#pragma unroll
    for (int r = 0; r < 4; ++r) {
      int srow = tB*64 + w*16 + l4*4 + r;
      AOh[(size_t)srow * (H_*HD_) + n*16 + l15] = f2bf(o[n][r] / lrow[r]);
    }
}

extern "C" void kernel_launch(void* const* d_in, const int* in_sizes, int n_in,
                              void* d_out, int out_size, void* d_ws, size_t ws_size,
                              hipStream_t stream) {
  (void)in_sizes; (void)n_in; (void)out_size; (void)ws_size;
  const float* x   = (const float*)d_in[0];
  const int*   sid = (const int*)  d_in[1];
  // d_in[2] = cache (dead), d_in[3] = mask (dead: causal re-derived)
  const float* Wq  = (const float*)d_in[4];
  const float* bq  = (const float*)d_in[5];
  const float* Wk  = (const float*)d_in[6];
  const float* bk  = (const float*)d_in[7];
  const float* Wv  = (const float*)d_in[8];
  const float* bv  = (const float*)d_in[9];
  const float* Wo  = (const float*)d_in[10];
  float* out = (float*)d_out;

  char* ws = (char*)d_ws;
  u16*   xb   = (u16*)  (ws);                    // 16 MB (aliased by AO later)
  u16*   WB   = (u16*)  (ws + 16777216);         // 48 MB  [6144][4096]
  u16*   WoT  = (u16*)  (ws + 67108864);         // 32 MB  [4096][4096]
  u16*   qb   = (u16*)  (ws + 150994944);        // 16 MB  [B][H][S][HD]
  u16*   kb   = (u16*)  (ws + 167772160);        //  4 MB  [B][KVH][S][HD]
  u16*   vb   = (u16*)  (ws + 171966464);        //  4 MB
  u16*   VT   = (u16*)  (ws + 176160768);        //  4 MB  [B][KVH][HD][S]
  float* cosd = (float*)(ws + 180355072);        // 256 KB
  float* sind = (float*)(ws + 180617216);        // 256 KB
  u16*   AO   = xb;                              // attention output reuses xb

  dim3 tb(32, 8);
  k_convert<<<8192, 256, 0, stream>>>(x, xb, (2048*4096)/4);
  k_transpose_w<<<dim3(64,64), 256, 0, stream>>>(Wq, WB, 4096, 4096);
  k_transpose_w<<<dim3(16,64), 256, 0, stream>>>(Wk, WB + (size_t)4096*4096, 4096, 1024);
  k_transpose_w<<<dim3(16,64), 256, 0, stream>>>(Wv, WB + (size_t)5120*4096, 4096, 1024);
  k_transpose_w<<<dim3(64,64), 256, 0, stream>>>(Wo, WoT, 4096, 4096);
  k_rope<<<256, 256, 0, stream>>>(sid, cosd, sind);
  k_gemmq<<<192, 512, 0, stream>>>(xb, WB, bq, bk, bv, cosd, sind, qb, kb, vb);
  k_transpose_v<<<dim3(32,4,16), tb, 0, stream>>>(vb, VT);
  k_attn<<<512, 256, 0, stream>>>(qb, kb, VT, AO);
  k_gemmo<<<256, 512, 0, stream>>>(AO, WoT, out, 4096, 4096);
}